// Round 4
// baseline (1844.525 us; speedup 1.0000x reference)
//
#include <hip/hip_runtime.h>

// ---------------------------------------------------------------------------
// RelationalDynamics fp32 pipeline for MI355X.
// B=2048, K=16, Z=128, DIM=256, BK_ALL = B*K = 32768 rows.
//
// Algebra: eff = elu(h_i@WeL.T + h_j@WeR.T + be)  with
//   WeL = We[:, :128]+We[:,128:256], WeR = We[:,256:384]+We[:,384:512]
// => precompute U=h@WeL.T, V=h@WeR.T per object; pairs become elementwise.
// rel = h@(WcA).T + E@(WcB).T + bc with WcA = Wc[:, :128]+Wc[:,128:256].
//
// Round-2 changes (from counters: pair_kernel 387us VALU-bound, 1.2e7 bank
// conflicts; GEMMs ~32% of fp32 peak):
//  * pair_kernel: one elu per pair-dim (was 3x), lane owns stride-64 dims
//    (bank = lane mod 32, 2-way = free), E accumulated in LDS via ds_add_f32
//    atomics. 1024 threads / 1 batch per block.
//  * GEMMs: 128x128 tile, 8x8 microtile (64 FMA per 4 ds_read_b128).
// ---------------------------------------------------------------------------

__device__ __forceinline__ float eluf(float x) { return x > 0.0f ? x : expm1f(x); }
__device__ __forceinline__ float sigmoidf_(float x) { return 1.0f / (1.0f + expf(-x)); }

// ------------------------- weight prep -------------------------------------
__global__ __launch_bounds__(256) void prep_kernel(
    const float* __restrict__ We, const float* __restrict__ Wc,
    const float* __restrict__ Wl, const float* __restrict__ Wsc,
    const float* __restrict__ Wh, const float* __restrict__ bl,
    const float* __restrict__ bs, const float* __restrict__ bh,
    float* __restrict__ WUVT, float* __restrict__ Wrel,
    float* __restrict__ Wlsh, float* __restrict__ blsh)
{
  int idx = blockIdx.x * 256 + threadIdx.x;
  if (idx < 131072) {
    int d = idx >> 10, o = idx & 1023;
    float v;
    if (o < 512) v = We[o * 512 + d] + We[o * 512 + d + 128];
    else { int oo = o - 512; v = We[oo * 512 + d + 256] + We[oo * 512 + d + 384]; }
    WUVT[idx] = v;
  } else if (idx < 212992) {               // 131072 + 81920
    int j = idx - 131072; int o = j / 640, c = j - o * 640;
    Wrel[j] = (c < 128) ? (Wc[o * 768 + c] + Wc[o * 768 + c + 128])
                        : Wc[o * 768 + c + 128];
  } else if (idx < 262144) {               // + 49152
    int j = idx - 212992; int o = j >> 7, c = j & 127;
    Wlsh[j] = (o < 128) ? Wl[o * 128 + c]
            : (o < 256) ? Wsc[(o - 128) * 128 + c]
                        : Wh[(o - 256) * 128 + c];
  } else if (idx < 262528) {
    int j = idx - 262144;
    blsh[j] = (j < 128) ? bl[j] : (j < 256) ? bs[j - 128] : bh[j - 256];
  }
}

// ------------------------- 128x128 tiled GEMM ------------------------------
// C[M,N] = act(A[M,K] @ W.T + bias), W is [N][K] row-major.
// 256 threads, 8x8 microtile (split rows {tr*4, 64+tr*4}, cols likewise).
// grid = (M/128, N/128). ACT: 0 none, 1 elu.
// OUTMODE 0 -> C[r*ldc+c]; OUTMODE 1 -> c<256: C[r*256+c], else C2[r*128+c-256].
template<int ACT, int OUTMODE>
__global__ __launch_bounds__(256) void gemm_kernel(
    const float* __restrict__ A, int lda,
    const float* __restrict__ W, int K,
    const float* __restrict__ bias,
    float* __restrict__ C, int ldc, float* __restrict__ C2)
{
  __shared__ float As[32][132];   // k-major; 132*4B row: 16B-aligned, banks ok
  __shared__ float Bs[32][132];
  const int t = threadIdx.x;
  const int tr = t >> 4, tc = t & 15;
  const int row0 = blockIdx.x * 128, col0 = blockIdx.y * 128;
  float acc[8][8];
#pragma unroll
  for (int i = 0; i < 8; ++i)
#pragma unroll
    for (int j = 0; j < 8; ++j) acc[i][j] = 0.f;

  for (int kk = 0; kk < K; kk += 32) {
#pragma unroll
    for (int i = 0; i < 4; ++i) {
      int f = t + i * 256;                 // 0..1023
      int r = f >> 3, k4 = (f & 7) << 2;   // r 0..127, k4 0..28
      float4 va = *(const float4*)(A + (size_t)(row0 + r) * lda + kk + k4);
      As[k4 + 0][r] = va.x; As[k4 + 1][r] = va.y;
      As[k4 + 2][r] = va.z; As[k4 + 3][r] = va.w;
      float4 vw = *(const float4*)(W + (size_t)(col0 + r) * K + kk + k4);
      Bs[k4 + 0][r] = vw.x; Bs[k4 + 1][r] = vw.y;
      Bs[k4 + 2][r] = vw.z; Bs[k4 + 3][r] = vw.w;
    }
    __syncthreads();
#pragma unroll
    for (int k = 0; k < 32; ++k) {
      float4 a0 = *(const float4*)&As[k][tr << 2];
      float4 a1 = *(const float4*)&As[k][64 + (tr << 2)];
      float4 b0 = *(const float4*)&Bs[k][tc << 2];
      float4 b1 = *(const float4*)&Bs[k][64 + (tc << 2)];
      float ar[8] = {a0.x, a0.y, a0.z, a0.w, a1.x, a1.y, a1.z, a1.w};
      float br[8] = {b0.x, b0.y, b0.z, b0.w, b1.x, b1.y, b1.z, b1.w};
#pragma unroll
      for (int ri = 0; ri < 8; ++ri)
#pragma unroll
        for (int ci = 0; ci < 8; ++ci)
          acc[ri][ci] = fmaf(ar[ri], br[ci], acc[ri][ci]);
    }
    __syncthreads();
  }

#pragma unroll
  for (int ri = 0; ri < 8; ++ri) {
    int r = row0 + ((ri < 4) ? ((tr << 2) + ri) : (64 + (tr << 2) + ri - 4));
#pragma unroll
    for (int half = 0; half < 2; ++half) {
      int c = col0 + (half ? 64 : 0) + (tc << 2);
      float vv[4];
#pragma unroll
      for (int u = 0; u < 4; ++u) {
        float x = acc[ri][half * 4 + u] + bias[c + u];
        if (ACT == 1) x = x > 0.f ? x : expm1f(x);
        vv[u] = x;
      }
      float4 v; v.x = vv[0]; v.y = vv[1]; v.z = vv[2]; v.w = vv[3];
      if (OUTMODE == 0) {
        *(float4*)(C + (size_t)r * ldc + c) = v;
      } else {
        if (c < 256) *(float4*)(C + (size_t)r * 256 + c) = v;
        else         *(float4*)(C2 + (size_t)r * 128 + (c - 256)) = v;
      }
    }
  }
}

// ------------------------- GRU gates ---------------------------------------
// h_new = (1-u)*n + u*h0 ; writes h_new into Acat[:, 0:128] (ld=640)
__global__ __launch_bounds__(256) void gru_gates_kernel(
    const float* __restrict__ gi, const float* __restrict__ gh,
    const float* __restrict__ h0, float* __restrict__ Acat)
{
  int g = blockIdx.x * 256 + threadIdx.x;   // 32768*32 threads
  int r = g >> 5, c = (g & 31) << 2;
  const float* gir = gi + (size_t)r * 384;
  const float* ghr = gh + (size_t)r * 384;
  float4 ir  = *(const float4*)(gir + c);
  float4 iz  = *(const float4*)(gir + 128 + c);
  float4 in_ = *(const float4*)(gir + 256 + c);
  float4 hr  = *(const float4*)(ghr + c);
  float4 hz  = *(const float4*)(ghr + 128 + c);
  float4 hn  = *(const float4*)(ghr + 256 + c);
  float4 h   = *(const float4*)(h0 + (size_t)r * 128 + c);
  float4 o;
  {
    float rg = sigmoidf_(ir.x + hr.x), u = sigmoidf_(iz.x + hz.x);
    float n = tanhf(in_.x + rg * hn.x);
    o.x = (1.f - u) * n + u * h.x;
  }
  {
    float rg = sigmoidf_(ir.y + hr.y), u = sigmoidf_(iz.y + hz.y);
    float n = tanhf(in_.y + rg * hn.y);
    o.y = (1.f - u) * n + u * h.y;
  }
  {
    float rg = sigmoidf_(ir.z + hr.z), u = sigmoidf_(iz.z + hz.z);
    float n = tanhf(in_.z + rg * hn.z);
    o.z = (1.f - u) * n + u * h.z;
  }
  {
    float rg = sigmoidf_(ir.w + hr.w), u = sigmoidf_(iz.w + hz.w);
    float n = tanhf(in_.w + rg * hn.w);
    o.w = (1.f - u) * n + u * h.w;
  }
  *(float4*)(Acat + (size_t)r * 640 + c) = o;
}

// ------------------------- fused pair kernel -------------------------------
// One block (1024 threads, 16 waves) per batch b.
// Phase 1: UV = h @ WUVT  (thread t owns col t of [16][1024]).
// Phase 2: each wave takes pairs p = w + 16q; lane l owns dims {l+64u}.
//   e8 = elu(U[i]+V[j]+be) computed ONCE; att via shfl_xor reduce;
//   att*e8 scatter-added to E_lds[i], E_lds[j] via LDS atomics.
// Phase 3: E_lds -> Acat[:, 128:640].
// LDS ~110KB -> 1 block/CU (16 waves/CU, 4/SIMD).
__global__ __launch_bounds__(1024) void pair_kernel(
    float* __restrict__ Acat,
    const float* __restrict__ WUVT,   // [128][1024]
    const float* __restrict__ be, const float* __restrict__ Wa,
    const float* __restrict__ ba)
{
  __shared__ float hT[128][20];       // hT[d][k] = h[k][d]; 20-pad: 16B align
  __shared__ float UV[16 * 1024];     // [k][0:512]=U, [k][512:1024]=V
  __shared__ float E_l[16 * 512];
  __shared__ int ii_l[120], jj_l[120];
  const int b = blockIdx.x, t = threadIdx.x;
  const int w = t >> 6, l = t & 63;

  if (t < 512) {
    int k = t >> 5, c4 = (t & 31) << 2;
    float4 h4 = *(const float4*)(Acat + (size_t)(b * 16 + k) * 640 + c4);
    hT[c4 + 0][k] = h4.x; hT[c4 + 1][k] = h4.y;
    hT[c4 + 2][k] = h4.z; hT[c4 + 3][k] = h4.w;
  } else if (t < 632) {
    int p = t - 512, i = 0, rem = p;
    while (rem >= 15 - i) { rem -= 15 - i; ++i; }
    ii_l[p] = i; jj_l[p] = i + 1 + rem;
  }
  {
    float4 z4 = {0.f, 0.f, 0.f, 0.f};
    *(float4*)&E_l[(t << 2)] = z4;
    *(float4*)&E_l[4096 + (t << 2)] = z4;
  }
  float be8[8], wa8[8];
#pragma unroll
  for (int u = 0; u < 8; ++u) {
    be8[u] = be[l + 64 * u];
    wa8[u] = Wa[l + 64 * u];
  }
  const float ba0 = ba[0];
  __syncthreads();

  // ---- UV phase: thread t owns output col t
  {
    float acc[16];
#pragma unroll
    for (int k = 0; k < 16; ++k) acc[k] = 0.f;
#pragma unroll 2
    for (int d = 0; d < 128; ++d) {
      float wv = WUVT[d * 1024 + t];
      float4 h0 = *(const float4*)&hT[d][0];
      float4 h1 = *(const float4*)&hT[d][4];
      float4 h2 = *(const float4*)&hT[d][8];
      float4 h3 = *(const float4*)&hT[d][12];
      acc[0]  = fmaf(h0.x, wv, acc[0]);  acc[1]  = fmaf(h0.y, wv, acc[1]);
      acc[2]  = fmaf(h0.z, wv, acc[2]);  acc[3]  = fmaf(h0.w, wv, acc[3]);
      acc[4]  = fmaf(h1.x, wv, acc[4]);  acc[5]  = fmaf(h1.y, wv, acc[5]);
      acc[6]  = fmaf(h1.z, wv, acc[6]);  acc[7]  = fmaf(h1.w, wv, acc[7]);
      acc[8]  = fmaf(h2.x, wv, acc[8]);  acc[9]  = fmaf(h2.y, wv, acc[9]);
      acc[10] = fmaf(h2.z, wv, acc[10]); acc[11] = fmaf(h2.w, wv, acc[11]);
      acc[12] = fmaf(h3.x, wv, acc[12]); acc[13] = fmaf(h3.y, wv, acc[13]);
      acc[14] = fmaf(h3.z, wv, acc[14]); acc[15] = fmaf(h3.w, wv, acc[15]);
    }
#pragma unroll
    for (int k = 0; k < 16; ++k) UV[k * 1024 + t] = acc[k];
  }
  __syncthreads();

  // ---- pair phase: wave w -> pairs p = w, w+16, ..., lane l -> dims {l+64u}
  for (int q = 0; q < 8; ++q) {
    int p = (q << 4) + w;
    if (p < 120) {                       // wave-uniform branch
      int i = ii_l[p], j = jj_l[p];
      const float* Ui = &UV[i * 1024];
      const float* Vj = &UV[j * 1024 + 512];
      float e[8]; float s = 0.f;
#pragma unroll
      for (int u = 0; u < 8; ++u) {
        float x = Ui[l + 64 * u] + Vj[l + 64 * u] + be8[u];
        float ev = eluf(x);
        e[u] = ev;
        s = fmaf(ev, wa8[u], s);
      }
#pragma unroll
      for (int off = 1; off < 64; off <<= 1) s += __shfl_xor(s, off, 64);
      float att = sigmoidf_(s + ba0);
#pragma unroll
      for (int u = 0; u < 8; ++u) {
        float wv = att * e[u];
        atomicAdd(&E_l[i * 512 + l + 64 * u], wv);
        atomicAdd(&E_l[j * 512 + l + 64 * u], wv);
      }
    }
  }
  __syncthreads();

  // ---- write E -> Acat[:, 128:640]
#pragma unroll
  for (int i = 0; i < 2; ++i) {
    int f = t + i * 1024;
    int k = f >> 7, c4 = (f & 127) << 2;
    *(float4*)(Acat + (size_t)(b * 16 + k) * 640 + 128 + c4) =
        *(const float4*)&E_l[k * 512 + c4];
  }
}

// ---------------------------------------------------------------------------
extern "C" void kernel_launch(void* const* d_in, const int* in_sizes, int n_in,
                              void* d_out, int out_size, void* d_ws, size_t ws_size,
                              hipStream_t stream)
{
  (void)in_sizes; (void)n_in; (void)out_size; (void)ws_size;
  const float* z     = (const float*)d_in[0];
  const float* h0    = (const float*)d_in[1];
  const float* W_obj = (const float*)d_in[2];
  const float* b_obj = (const float*)d_in[3];
  const float* Wih   = (const float*)d_in[4];
  const float* bih   = (const float*)d_in[5];
  const float* Whh   = (const float*)d_in[6];
  const float* bhh   = (const float*)d_in[7];
  const float* We    = (const float*)d_in[8];
  const float* be    = (const float*)d_in[9];
  const float* Wa    = (const float*)d_in[10];
  const float* ba    = (const float*)d_in[11];
  const float* Wc    = (const float*)d_in[12];
  const float* bc    = (const float*)d_in[13];
  const float* Wl    = (const float*)d_in[14];
  const float* bl    = (const float*)d_in[15];
  const float* Wsc   = (const float*)d_in[16];
  const float* bs    = (const float*)d_in[17];
  const float* Wh    = (const float*)d_in[18];
  const float* bh    = (const float*)d_in[19];

  float* ws  = (float*)d_ws;
  float* out = (float*)d_out;

  // workspace layout (floats); rel aliases x (x dead after gi GEMM)
  float* x    = ws;                  //  8,388,608  [32768][256]
  float* gi   = ws + 8388608;        // 12,582,912  [32768][384]
  float* gh   = ws + 20971520;       // 12,582,912  [32768][384]
  float* Acat = ws + 33554432;       // 20,971,520  [32768][640] = [h_new | E]
  float* WUVT = ws + 54525952;       //    131,072  [128][1024]
  float* Wrel = ws + 54657024;       //     81,920  [128][640]
  float* Wlsh = ws + 54738944;       //     49,152  [384][128]
  float* blsh = ws + 54788096;       //        384
  float* rel  = x;                   //  4,194,304  [32768][128]

  prep_kernel<<<1026, 256, 0, stream>>>(We, Wc, Wl, Wsc, Wh, bl, bs, bh,
                                        WUVT, Wrel, Wlsh, blsh);
  // x = elu(z @ W_obj.T + b_obj)            [32768,128]x[256,128]
  gemm_kernel<1,0><<<dim3(256, 2), 256, 0, stream>>>(z, 128, W_obj, 128, b_obj, x, 256, nullptr);
  // gi = x @ Wih.T + bih                    [32768,256]x[384,256]
  gemm_kernel<0,0><<<dim3(256, 3), 256, 0, stream>>>(x, 256, Wih, 256, bih, gi, 384, nullptr);
  // gh = h0 @ Whh.T + bhh                   [32768,128]x[384,128]
  gemm_kernel<0,0><<<dim3(256, 3), 256, 0, stream>>>(h0, 128, Whh, 128, bhh, gh, 384, nullptr);
  // GRU gates -> h_new into Acat[:,0:128]
  gru_gates_kernel<<<4096, 256, 0, stream>>>(gi, gh, h0, Acat);
  // per-batch: U,V -> att -> E into Acat[:,128:640]
  pair_kernel<<<2048, 1024, 0, stream>>>(Acat, WUVT, be, Wa, ba);
  // rel = Acat @ Wrel.T + bc                [32768,640]x[128,640]
  gemm_kernel<0,0><<<dim3(256, 1), 256, 0, stream>>>(Acat, 640, Wrel, 640, bc, rel, 128, nullptr);
  // [loc|scale|h_out] = rel @ Wlsh.T + blsh, scattered into d_out
  gemm_kernel<0,1><<<dim3(256, 3), 256, 0, stream>>>(rel, 128, Wlsh, 128, blsh, out, 0, out + 8388608);
}

// Round 6
// 631.064 us; speedup vs baseline: 2.9229x; 2.9229x over previous
//
#include <hip/hip_runtime.h>

// ---------------------------------------------------------------------------
// RelationalDynamics fp32 pipeline for MI355X.
// B=2048, K=16, Z=128, DIM=256, BK_ALL = B*K = 32768 rows.
//
// Algebra: eff = elu(h_i@WeL.T + h_j@WeR.T + be)  with
//   WeL = We[:, :128]+We[:,128:256], WeR = We[:,256:384]+We[:,384:512]
// => precompute U=h@WeL.T, V=h@WeR.T per object; pairs become elementwise.
// rel = h@(WcA).T + E@(WcB).T + bc with WcA = Wc[:, :128]+Wc[:,128:256].
//
// Round-4 post-mortem: LDS float atomicAdd scatter (round-2 design) collapsed
// VALUBusy to 13.6% (1507us) — all-wave same-address LDS atomic RMW
// serializes (or CAS-loops). Round-5: GATHER form — wave w owns objects
// {2w,2w+1}, recomputes eff per ordered (k,m) (2x elu, vs 3x in the 387us
// round-1 kernel), att inline via shfl reduce, E in registers, no atomics.
// All LDS accesses b128 conflict-free. Fast transcendentals (v_exp/v_rcp):
// absmax headroom is 2^-7, exp-based elu/sigmoid/tanh are ~1e-6 accurate.
// ---------------------------------------------------------------------------

__device__ __forceinline__ float fast_exp(float x) { return __expf(x); }
__device__ __forceinline__ float eluf(float x) {
  return x > 0.0f ? x : fast_exp(x) - 1.0f;
}
__device__ __forceinline__ float sigmoidf_(float x) {
  return __builtin_amdgcn_rcpf(1.0f + fast_exp(-x));
}
__device__ __forceinline__ float tanhf_(float x) {
  // tanh(x) = 1 - 2/(exp(2x)+1); exp overflow/underflow saturates correctly
  return 1.0f - 2.0f * __builtin_amdgcn_rcpf(fast_exp(2.0f * x) + 1.0f);
}

// ------------------------- weight prep -------------------------------------
__global__ __launch_bounds__(256) void prep_kernel(
    const float* __restrict__ We, const float* __restrict__ Wc,
    const float* __restrict__ Wl, const float* __restrict__ Wsc,
    const float* __restrict__ Wh, const float* __restrict__ bl,
    const float* __restrict__ bs, const float* __restrict__ bh,
    float* __restrict__ WUVT, float* __restrict__ Wrel,
    float* __restrict__ Wlsh, float* __restrict__ blsh)
{
  int idx = blockIdx.x * 256 + threadIdx.x;
  if (idx < 131072) {
    int d = idx >> 10, o = idx & 1023;
    float v;
    if (o < 512) v = We[o * 512 + d] + We[o * 512 + d + 128];
    else { int oo = o - 512; v = We[oo * 512 + d + 256] + We[oo * 512 + d + 384]; }
    WUVT[idx] = v;
  } else if (idx < 212992) {               // 131072 + 81920
    int j = idx - 131072; int o = j / 640, c = j - o * 640;
    Wrel[j] = (c < 128) ? (Wc[o * 768 + c] + Wc[o * 768 + c + 128])
                        : Wc[o * 768 + c + 128];
  } else if (idx < 262144) {               // + 49152
    int j = idx - 212992; int o = j >> 7, c = j & 127;
    Wlsh[j] = (o < 128) ? Wl[o * 128 + c]
            : (o < 256) ? Wsc[(o - 128) * 128 + c]
                        : Wh[(o - 256) * 128 + c];
  } else if (idx < 262528) {
    int j = idx - 262144;
    blsh[j] = (j < 128) ? bl[j] : (j < 256) ? bs[j - 128] : bh[j - 256];
  }
}

// ------------------------- 128x128 tiled GEMM ------------------------------
// C[M,N] = act(A[M,K] @ W.T + bias), W is [N][K] row-major.
// 256 threads, 8x8 microtile (split rows {tr*4, 64+tr*4}, cols likewise).
// grid = (M/128, N/128). ACT: 0 none, 1 elu.
// OUTMODE 0 -> C[r*ldc+c]; OUTMODE 1 -> c<256: C[r*256+c], else C2[r*128+c-256].
template<int ACT, int OUTMODE>
__global__ __launch_bounds__(256) void gemm_kernel(
    const float* __restrict__ A, int lda,
    const float* __restrict__ W, int K,
    const float* __restrict__ bias,
    float* __restrict__ C, int ldc, float* __restrict__ C2)
{
  __shared__ float As[32][132];   // k-major; 132*4B row: 16B-aligned, banks ok
  __shared__ float Bs[32][132];
  const int t = threadIdx.x;
  const int tr = t >> 4, tc = t & 15;
  const int row0 = blockIdx.x * 128, col0 = blockIdx.y * 128;
  float acc[8][8];
#pragma unroll
  for (int i = 0; i < 8; ++i)
#pragma unroll
    for (int j = 0; j < 8; ++j) acc[i][j] = 0.f;

  for (int kk = 0; kk < K; kk += 32) {
#pragma unroll
    for (int i = 0; i < 4; ++i) {
      int f = t + i * 256;                 // 0..1023
      int r = f >> 3, k4 = (f & 7) << 2;   // r 0..127, k4 0..28
      float4 va = *(const float4*)(A + (size_t)(row0 + r) * lda + kk + k4);
      As[k4 + 0][r] = va.x; As[k4 + 1][r] = va.y;
      As[k4 + 2][r] = va.z; As[k4 + 3][r] = va.w;
      float4 vw = *(const float4*)(W + (size_t)(col0 + r) * K + kk + k4);
      Bs[k4 + 0][r] = vw.x; Bs[k4 + 1][r] = vw.y;
      Bs[k4 + 2][r] = vw.z; Bs[k4 + 3][r] = vw.w;
    }
    __syncthreads();
#pragma unroll
    for (int k = 0; k < 32; ++k) {
      float4 a0 = *(const float4*)&As[k][tr << 2];
      float4 a1 = *(const float4*)&As[k][64 + (tr << 2)];
      float4 b0 = *(const float4*)&Bs[k][tc << 2];
      float4 b1 = *(const float4*)&Bs[k][64 + (tc << 2)];
      float ar[8] = {a0.x, a0.y, a0.z, a0.w, a1.x, a1.y, a1.z, a1.w};
      float br[8] = {b0.x, b0.y, b0.z, b0.w, b1.x, b1.y, b1.z, b1.w};
#pragma unroll
      for (int ri = 0; ri < 8; ++ri)
#pragma unroll
        for (int ci = 0; ci < 8; ++ci)
          acc[ri][ci] = fmaf(ar[ri], br[ci], acc[ri][ci]);
    }
    __syncthreads();
  }

#pragma unroll
  for (int ri = 0; ri < 8; ++ri) {
    int r = row0 + ((ri < 4) ? ((tr << 2) + ri) : (64 + (tr << 2) + ri - 4));
#pragma unroll
    for (int half = 0; half < 2; ++half) {
      int c = col0 + (half ? 64 : 0) + (tc << 2);
      float vv[4];
#pragma unroll
      for (int u = 0; u < 4; ++u) {
        float x = acc[ri][half * 4 + u] + bias[c + u];
        if (ACT == 1) x = eluf(x);
        vv[u] = x;
      }
      float4 v; v.x = vv[0]; v.y = vv[1]; v.z = vv[2]; v.w = vv[3];
      if (OUTMODE == 0) {
        *(float4*)(C + (size_t)r * ldc + c) = v;
      } else {
        if (c < 256) *(float4*)(C + (size_t)r * 256 + c) = v;
        else         *(float4*)(C2 + (size_t)r * 128 + (c - 256)) = v;
      }
    }
  }
}

// ------------------------- GRU gates ---------------------------------------
// h_new = (1-u)*n + u*h0 ; writes h_new into Acat[:, 0:128] (ld=640)
__global__ __launch_bounds__(256) void gru_gates_kernel(
    const float* __restrict__ gi, const float* __restrict__ gh,
    const float* __restrict__ h0, float* __restrict__ Acat)
{
  int g = blockIdx.x * 256 + threadIdx.x;   // 32768*32 threads
  int r = g >> 5, c = (g & 31) << 2;
  const float* gir = gi + (size_t)r * 384;
  const float* ghr = gh + (size_t)r * 384;
  float4 ir  = *(const float4*)(gir + c);
  float4 iz  = *(const float4*)(gir + 128 + c);
  float4 in_ = *(const float4*)(gir + 256 + c);
  float4 hr  = *(const float4*)(ghr + c);
  float4 hz  = *(const float4*)(ghr + 128 + c);
  float4 hn  = *(const float4*)(ghr + 256 + c);
  float4 h   = *(const float4*)(h0 + (size_t)r * 128 + c);
  float4 o;
  {
    float rg = sigmoidf_(ir.x + hr.x), u = sigmoidf_(iz.x + hz.x);
    float n = tanhf_(in_.x + rg * hn.x);
    o.x = (1.f - u) * n + u * h.x;
  }
  {
    float rg = sigmoidf_(ir.y + hr.y), u = sigmoidf_(iz.y + hz.y);
    float n = tanhf_(in_.y + rg * hn.y);
    o.y = (1.f - u) * n + u * h.y;
  }
  {
    float rg = sigmoidf_(ir.z + hr.z), u = sigmoidf_(iz.z + hz.z);
    float n = tanhf_(in_.z + rg * hn.z);
    o.z = (1.f - u) * n + u * h.z;
  }
  {
    float rg = sigmoidf_(ir.w + hr.w), u = sigmoidf_(iz.w + hz.w);
    float n = tanhf_(in_.w + rg * hn.w);
    o.w = (1.f - u) * n + u * h.w;
  }
  *(float4*)(Acat + (size_t)r * 640 + c) = o;
}

// ------------------------- fused pair kernel (gather) ----------------------
// One block (512 threads, 8 waves) per batch b.
// Phase 1: UV = h @ WUVT  (thread t owns cols {t, t+512} of [16][1024]).
// Phase 2: wave w gathers E for objects k in {2w, 2w+1}:
//   for each partner m: e = elu(U[i]+V[j]+be) (computed once per (k,m)),
//   att = sigmoid(<e,Wa>+ba) via shfl_xor reduce, accE += att*e.
//   Lane l owns dims {4l..4l+3, 256+4l..256+4l+3} -> all b128, conflict-free.
// No atomics, no LDS E. LDS ~74KB -> 2 blocks/CU.
__global__ __launch_bounds__(512) void pair_kernel(
    float* __restrict__ Acat,
    const float* __restrict__ WUVT,   // [128][1024]
    const float* __restrict__ be, const float* __restrict__ Wa,
    const float* __restrict__ ba)
{
  __shared__ float hT[128][20];       // hT[d][k] = h[k][d]; 80B rows, 16B align
  __shared__ float UV[16 * 1024];     // [k][0:512]=U, [k][512:1024]=V
  const int b = blockIdx.x, t = threadIdx.x;
  const int w = t >> 6, l = t & 63;

  {
    int k = t >> 5, c4 = (t & 31) << 2;
    float4 h4 = *(const float4*)(Acat + (size_t)(b * 16 + k) * 640 + c4);
    hT[c4 + 0][k] = h4.x; hT[c4 + 1][k] = h4.y;
    hT[c4 + 2][k] = h4.z; hT[c4 + 3][k] = h4.w;
  }
  // lane l owns dims {4l+0..3} and {256+4l+0..3}
  float4 beA = *(const float4*)(be + (l << 2));
  float4 beB = *(const float4*)(be + 256 + (l << 2));
  float4 waA = *(const float4*)(Wa + (l << 2));
  float4 waB = *(const float4*)(Wa + 256 + (l << 2));
  const float ba0 = ba[0];
  __syncthreads();

  // ---- UV phase: thread t owns output cols {t, t+512}
  {
    float acc[16][2];
#pragma unroll
    for (int k = 0; k < 16; ++k) { acc[k][0] = 0.f; acc[k][1] = 0.f; }
#pragma unroll 2
    for (int d = 0; d < 128; ++d) {
      float wv0 = WUVT[d * 1024 + t];
      float wv1 = WUVT[d * 1024 + t + 512];
      float4 h0 = *(const float4*)&hT[d][0];
      float4 h1 = *(const float4*)&hT[d][4];
      float4 h2 = *(const float4*)&hT[d][8];
      float4 h3 = *(const float4*)&hT[d][12];
      float hv[16] = {h0.x, h0.y, h0.z, h0.w, h1.x, h1.y, h1.z, h1.w,
                      h2.x, h2.y, h2.z, h2.w, h3.x, h3.y, h3.z, h3.w};
#pragma unroll
      for (int k = 0; k < 16; ++k) {
        acc[k][0] = fmaf(hv[k], wv0, acc[k][0]);
        acc[k][1] = fmaf(hv[k], wv1, acc[k][1]);
      }
    }
#pragma unroll
    for (int k = 0; k < 16; ++k) {
      UV[k * 1024 + t] = acc[k][0];
      UV[k * 1024 + t + 512] = acc[k][1];
    }
  }
  __syncthreads();

  // ---- gather phase: wave w -> objects {2w, 2w+1}
#pragma unroll
  for (int kk = 0; kk < 2; ++kk) {
    const int k = (w << 1) + kk;
    float accA[4] = {0.f, 0.f, 0.f, 0.f};
    float accB[4] = {0.f, 0.f, 0.f, 0.f};
#pragma unroll 1
    for (int m = 0; m < 16; ++m) {
      if (m == k) continue;
      int i = k < m ? k : m;
      int j = k < m ? m : k;
      const float* Ui = &UV[i * 1024 + (l << 2)];
      const float* Vj = &UV[j * 1024 + 512 + (l << 2)];
      float4 u0 = *(const float4*)Ui;
      float4 u1 = *(const float4*)(Ui + 256);
      float4 v0 = *(const float4*)Vj;
      float4 v1 = *(const float4*)(Vj + 256);
      float eA[4], eB[4];
      eA[0] = eluf(u0.x + v0.x + beA.x);
      eA[1] = eluf(u0.y + v0.y + beA.y);
      eA[2] = eluf(u0.z + v0.z + beA.z);
      eA[3] = eluf(u0.w + v0.w + beA.w);
      eB[0] = eluf(u1.x + v1.x + beB.x);
      eB[1] = eluf(u1.y + v1.y + beB.y);
      eB[2] = eluf(u1.z + v1.z + beB.z);
      eB[3] = eluf(u1.w + v1.w + beB.w);
      float s;
      s = eA[0] * waA.x;
      s = fmaf(eA[1], waA.y, s);
      s = fmaf(eA[2], waA.z, s);
      s = fmaf(eA[3], waA.w, s);
      s = fmaf(eB[0], waB.x, s);
      s = fmaf(eB[1], waB.y, s);
      s = fmaf(eB[2], waB.z, s);
      s = fmaf(eB[3], waB.w, s);
#pragma unroll
      for (int off = 1; off < 64; off <<= 1) s += __shfl_xor(s, off, 64);
      float att = sigmoidf_(s + ba0);
      accA[0] = fmaf(att, eA[0], accA[0]);
      accA[1] = fmaf(att, eA[1], accA[1]);
      accA[2] = fmaf(att, eA[2], accA[2]);
      accA[3] = fmaf(att, eA[3], accA[3]);
      accB[0] = fmaf(att, eB[0], accB[0]);
      accB[1] = fmaf(att, eB[1], accB[1]);
      accB[2] = fmaf(att, eB[2], accB[2]);
      accB[3] = fmaf(att, eB[3], accB[3]);
    }
    float* dst = Acat + (size_t)(b * 16 + k) * 640 + 128;
    float4 oA; oA.x = accA[0]; oA.y = accA[1]; oA.z = accA[2]; oA.w = accA[3];
    float4 oB; oB.x = accB[0]; oB.y = accB[1]; oB.z = accB[2]; oB.w = accB[3];
    *(float4*)(dst + (l << 2)) = oA;
    *(float4*)(dst + 256 + (l << 2)) = oB;
  }
}

// ---------------------------------------------------------------------------
extern "C" void kernel_launch(void* const* d_in, const int* in_sizes, int n_in,
                              void* d_out, int out_size, void* d_ws, size_t ws_size,
                              hipStream_t stream)
{
  (void)in_sizes; (void)n_in; (void)out_size; (void)ws_size;
  const float* z     = (const float*)d_in[0];
  const float* h0    = (const float*)d_in[1];
  const float* W_obj = (const float*)d_in[2];
  const float* b_obj = (const float*)d_in[3];
  const float* Wih   = (const float*)d_in[4];
  const float* bih   = (const float*)d_in[5];
  const float* Whh   = (const float*)d_in[6];
  const float* bhh   = (const float*)d_in[7];
  const float* We    = (const float*)d_in[8];
  const float* be    = (const float*)d_in[9];
  const float* Wa    = (const float*)d_in[10];
  const float* ba    = (const float*)d_in[11];
  const float* Wc    = (const float*)d_in[12];
  const float* bc    = (const float*)d_in[13];
  const float* Wl    = (const float*)d_in[14];
  const float* bl    = (const float*)d_in[15];
  const float* Wsc   = (const float*)d_in[16];
  const float* bs    = (const float*)d_in[17];
  const float* Wh    = (const float*)d_in[18];
  const float* bh    = (const float*)d_in[19];

  float* ws  = (float*)d_ws;
  float* out = (float*)d_out;

  // workspace layout (floats); rel aliases x (x dead after gi GEMM)
  float* x    = ws;                  //  8,388,608  [32768][256]
  float* gi   = ws + 8388608;        // 12,582,912  [32768][384]
  float* gh   = ws + 20971520;       // 12,582,912  [32768][384]
  float* Acat = ws + 33554432;       // 20,971,520  [32768][640] = [h_new | E]
  float* WUVT = ws + 54525952;       //    131,072  [128][1024]
  float* Wrel = ws + 54657024;       //     81,920  [128][640]
  float* Wlsh = ws + 54738944;       //     49,152  [384][128]
  float* blsh = ws + 54788096;       //        384
  float* rel  = x;                   //  4,194,304  [32768][128]

  prep_kernel<<<1026, 256, 0, stream>>>(We, Wc, Wl, Wsc, Wh, bl, bs, bh,
                                        WUVT, Wrel, Wlsh, blsh);
  // x = elu(z @ W_obj.T + b_obj)            [32768,128]x[256,128]
  gemm_kernel<1,0><<<dim3(256, 2), 256, 0, stream>>>(z, 128, W_obj, 128, b_obj, x, 256, nullptr);
  // gi = x @ Wih.T + bih                    [32768,256]x[384,256]
  gemm_kernel<0,0><<<dim3(256, 3), 256, 0, stream>>>(x, 256, Wih, 256, bih, gi, 384, nullptr);
  // gh = h0 @ Whh.T + bhh                   [32768,128]x[384,128]
  gemm_kernel<0,0><<<dim3(256, 3), 256, 0, stream>>>(h0, 128, Whh, 128, bhh, gh, 384, nullptr);
  // GRU gates -> h_new into Acat[:,0:128]
  gru_gates_kernel<<<4096, 256, 0, stream>>>(gi, gh, h0, Acat);
  // per-batch: U,V -> att -> E into Acat[:,128:640]  (gather, no atomics)
  pair_kernel<<<2048, 512, 0, stream>>>(Acat, WUVT, be, Wa, ba);
  // rel = Acat @ Wrel.T + bc                [32768,640]x[128,640]
  gemm_kernel<0,0><<<dim3(256, 1), 256, 0, stream>>>(Acat, 640, Wrel, 640, bc, rel, 128, nullptr);
  // [loc|scale|h_out] = rel @ Wlsh.T + blsh, scattered into d_out
  gemm_kernel<0,1><<<dim3(256, 3), 256, 0, stream>>>(rel, 128, Wlsh, 128, blsh, out, 0, out + 8388608);
}

// Round 10
// 523.934 us; speedup vs baseline: 3.5205x; 1.2045x over previous
//
#include <hip/hip_runtime.h>

// ---------------------------------------------------------------------------
// RelationalDynamics pipeline for MI355X — bf16-MFMA GEMM chain + fp32 pair.
// B=2048, K=16, Z=128, DIM=256, BK_ALL = 32768 rows.
//
// Round-6 counters: pair_kernel 230us (VALUBusy 83%), fp32 GEMMs ~390us at
// ~35% of the 157TF fp32 vector ceiling. CDNA4 has NO fp32 MFMA but 2.5PF
// bf16 MFMA -> convert all 5 GEMMs to mfma_f32_16x16x32_bf16 (m89-verified
// layouts: A[M][K] row-major, lane reads A[row0+(l&15)][k0+8*(l>>4)+0..7];
// W[N][K] row-major same pattern; D: C[row0+(l>>4)*4+j][col0+(l&15)]).
// Activations flow bf16; accumulation fp32. Direct-global fragment loads
// (weights L2-resident, activations L3), 64x64 tile / 4 waves, no LDS.
// ---------------------------------------------------------------------------

typedef __attribute__((ext_vector_type(8))) short bf16x8;
typedef __attribute__((ext_vector_type(4))) float f32x4;

__device__ __forceinline__ float fast_exp(float x) { return __expf(x); }
__device__ __forceinline__ float eluf(float x) {
  return x > 0.0f ? x : fast_exp(x) - 1.0f;
}
__device__ __forceinline__ float sigmoidf_(float x) {
  return __builtin_amdgcn_rcpf(1.0f + fast_exp(-x));
}
__device__ __forceinline__ float tanhf_(float x) {
  return 1.0f - 2.0f * __builtin_amdgcn_rcpf(fast_exp(2.0f * x) + 1.0f);
}
__device__ __forceinline__ short f2bf(float x) {        // RNE f32->bf16
  unsigned u = __builtin_bit_cast(unsigned, x);
  unsigned r = (u + 0x7FFFu + ((u >> 16) & 1u)) >> 16;
  return (short)r;
}
__device__ __forceinline__ float bf2f(short s) {
  return __builtin_bit_cast(float, ((unsigned)(unsigned short)s) << 16);
}

// ------------------------- weight prep -------------------------------------
// WUVT f32 [128][1024] (pair UV weights, transposed+folded We);
// Wrel_bf [128][640]; Wlsh_bf [384][128]; blsh f32 [384];
// Wobj_bf/Wih_bf/Whh_bf = direct bf16 casts.
__global__ __launch_bounds__(256) void prep_kernel(
    const float* __restrict__ We, const float* __restrict__ Wc,
    const float* __restrict__ Wl, const float* __restrict__ Wsc,
    const float* __restrict__ Wh, const float* __restrict__ bl,
    const float* __restrict__ bs, const float* __restrict__ bh,
    const float* __restrict__ W_obj, const float* __restrict__ Wih,
    const float* __restrict__ Whh,
    float* __restrict__ WUVT, float* __restrict__ blsh,
    short* __restrict__ Wrel_bf, short* __restrict__ Wlsh_bf,
    short* __restrict__ Wobj_bf, short* __restrict__ Wih_bf,
    short* __restrict__ Whh_bf)
{
  int idx = blockIdx.x * 256 + threadIdx.x;
  if (idx < 131072) {
    int d = idx >> 10, o = idx & 1023;
    float v;
    if (o < 512) v = We[o * 512 + d] + We[o * 512 + d + 128];
    else { int oo = o - 512; v = We[oo * 512 + d + 256] + We[oo * 512 + d + 384]; }
    WUVT[idx] = v;
  } else if (idx < 212992) {               // Wrel_bf: 81920
    int j = idx - 131072; int o = j / 640, c = j - o * 640;
    float v = (c < 128) ? (Wc[o * 768 + c] + Wc[o * 768 + c + 128])
                        : Wc[o * 768 + c + 128];
    Wrel_bf[j] = f2bf(v);
  } else if (idx < 262144) {               // Wlsh_bf: 49152
    int j = idx - 212992; int o = j >> 7, c = j & 127;
    float v = (o < 128) ? Wl[o * 128 + c]
            : (o < 256) ? Wsc[(o - 128) * 128 + c]
                        : Wh[(o - 256) * 128 + c];
    Wlsh_bf[j] = f2bf(v);
  } else if (idx < 262528) {               // blsh: 384
    int j = idx - 262144;
    blsh[j] = (j < 128) ? bl[j] : (j < 256) ? bs[j - 128] : bh[j - 256];
  } else if (idx < 295296) {               // Wobj_bf: 32768
    int j = idx - 262528; Wobj_bf[j] = f2bf(W_obj[j]);
  } else if (idx < 393600) {               // Wih_bf: 98304
    int j = idx - 295296; Wih_bf[j] = f2bf(Wih[j]);
  } else if (idx < 442752) {               // Whh_bf: 49152
    int j = idx - 393600; Whh_bf[j] = f2bf(Whh[j]);
  }
}

// ------------------------- z/h0 -> bf16 ------------------------------------
__global__ __launch_bounds__(256) void cvt_zh_kernel(
    const float* __restrict__ z, const float* __restrict__ h0,
    short* __restrict__ z_bf, short* __restrict__ h0_bf)
{
  int g = blockIdx.x * 256 + threadIdx.x;   // 2,097,152 threads x 4 elems
  const float* src; short* dst; int off;
  if (g < 1048576) { src = z;  dst = z_bf;  off = g << 2; }
  else             { src = h0; dst = h0_bf; off = (g - 1048576) << 2; }
  float4 v = *(const float4*)(src + off);
  short4 o;
  o.x = f2bf(v.x); o.y = f2bf(v.y); o.z = f2bf(v.z); o.w = f2bf(v.w);
  *(short4*)(dst + off) = o;
}

// ------------------------- bf16 MFMA GEMM ----------------------------------
// C[M,N] = act(A[M,K](bf16) @ W[N,K](bf16).T + bias).  64x64 tile, 4 waves;
// wave w owns rows [bx*64+w*16, +16) x cols [by*64, +64) as 4 col-tiles.
// ACT: 0 none, 1 elu.  OUTMODE: 0 f32->C[r*ldc+c]; 1 bf16->Cb[r*ldc+c];
// 2 split: c<256 -> C[r*256+c] (f32), else C2[r*128+c-256] (f32).
template<int ACT, int OUTMODE>
__global__ __launch_bounds__(256) void mfma_gemm(
    const short* __restrict__ A, int K,
    const short* __restrict__ W,
    const float* __restrict__ bias,
    float* __restrict__ C, int ldc,
    short* __restrict__ Cb,
    float* __restrict__ C2)
{
  const int t = threadIdx.x;
  const int wv = t >> 6, l = t & 63;
  const int lr = l & 15, lk = l >> 4;
  const int row0 = blockIdx.x * 64 + wv * 16;
  const int col0 = blockIdx.y * 64;

  const short* Ap = A + (size_t)(row0 + lr) * K + lk * 8;
  const short* Wp = W + (size_t)(col0 + lr) * K + lk * 8;
  const size_t wstep = (size_t)16 * K;

  f32x4 acc0 = {0.f,0.f,0.f,0.f}, acc1 = {0.f,0.f,0.f,0.f};
  f32x4 acc2 = {0.f,0.f,0.f,0.f}, acc3 = {0.f,0.f,0.f,0.f};
  for (int k0 = 0; k0 < K; k0 += 32) {
    bf16x8 a  = *(const bf16x8*)(Ap + k0);
    bf16x8 b0 = *(const bf16x8*)(Wp + k0);
    bf16x8 b1 = *(const bf16x8*)(Wp + wstep + k0);
    bf16x8 b2 = *(const bf16x8*)(Wp + 2 * wstep + k0);
    bf16x8 b3 = *(const bf16x8*)(Wp + 3 * wstep + k0);
    acc0 = __builtin_amdgcn_mfma_f32_16x16x32_bf16(a, b0, acc0, 0, 0, 0);
    acc1 = __builtin_amdgcn_mfma_f32_16x16x32_bf16(a, b1, acc1, 0, 0, 0);
    acc2 = __builtin_amdgcn_mfma_f32_16x16x32_bf16(a, b2, acc2, 0, 0, 0);
    acc3 = __builtin_amdgcn_mfma_f32_16x16x32_bf16(a, b3, acc3, 0, 0, 0);
  }
  f32x4 accs[4] = {acc0, acc1, acc2, acc3};
#pragma unroll
  for (int ct = 0; ct < 4; ++ct) {
    const int c = col0 + ct * 16 + lr;
    const float bv = bias[c];
#pragma unroll
    for (int j = 0; j < 4; ++j) {
      const int r = row0 + lk * 4 + j;
      float x = accs[ct][j] + bv;
      if (ACT == 1) x = eluf(x);
      if (OUTMODE == 0) {
        C[(size_t)r * ldc + c] = x;
      } else if (OUTMODE == 1) {
        Cb[(size_t)r * ldc + c] = f2bf(x);
      } else {
        if (c < 256) C[(size_t)r * 256 + c] = x;
        else         C2[(size_t)r * 128 + (c - 256)] = x;
      }
    }
  }
}

// ------------------------- GRU gates ---------------------------------------
// h_new = (1-u)*n + u*h0 ; writes h_new (bf16) into Acat_bf[:, 0:128] (ld=640)
__global__ __launch_bounds__(256) void gru_gates_kernel(
    const float* __restrict__ gi, const float* __restrict__ gh,
    const float* __restrict__ h0, short* __restrict__ Acat)
{
  int g = blockIdx.x * 256 + threadIdx.x;   // 32768*32 threads
  int r = g >> 5, c = (g & 31) << 2;
  const float* gir = gi + (size_t)r * 384;
  const float* ghr = gh + (size_t)r * 384;
  float4 ir  = *(const float4*)(gir + c);
  float4 iz  = *(const float4*)(gir + 128 + c);
  float4 in_ = *(const float4*)(gir + 256 + c);
  float4 hr  = *(const float4*)(ghr + c);
  float4 hz  = *(const float4*)(ghr + 128 + c);
  float4 hn  = *(const float4*)(ghr + 256 + c);
  float4 h   = *(const float4*)(h0 + (size_t)r * 128 + c);
  float4 o;
  {
    float rg = sigmoidf_(ir.x + hr.x), u = sigmoidf_(iz.x + hz.x);
    float n = tanhf_(in_.x + rg * hn.x);
    o.x = (1.f - u) * n + u * h.x;
  }
  {
    float rg = sigmoidf_(ir.y + hr.y), u = sigmoidf_(iz.y + hz.y);
    float n = tanhf_(in_.y + rg * hn.y);
    o.y = (1.f - u) * n + u * h.y;
  }
  {
    float rg = sigmoidf_(ir.z + hr.z), u = sigmoidf_(iz.z + hz.z);
    float n = tanhf_(in_.z + rg * hn.z);
    o.z = (1.f - u) * n + u * h.z;
  }
  {
    float rg = sigmoidf_(ir.w + hr.w), u = sigmoidf_(iz.w + hz.w);
    float n = tanhf_(in_.w + rg * hn.w);
    o.w = (1.f - u) * n + u * h.w;
  }
  short4 o4;
  o4.x = f2bf(o.x); o4.y = f2bf(o.y); o4.z = f2bf(o.z); o4.w = f2bf(o.w);
  *(short4*)(Acat + (size_t)r * 640 + c) = o4;
}

// ------------------------- fused pair kernel (gather) ----------------------
// One block (512 threads, 8 waves) per batch b.  Reads h (bf16) from Acat,
// UV = h@WUVT in fp32, gather E per object (no atomics), writes E bf16.
__global__ __launch_bounds__(512) void pair_kernel(
    short* __restrict__ Acat,
    const float* __restrict__ WUVT,   // [128][1024] f32
    const float* __restrict__ be, const float* __restrict__ Wa,
    const float* __restrict__ ba)
{
  __shared__ float hT[128][20];       // hT[d][k] = h[k][d]
  __shared__ float UV[16 * 1024];     // [k][0:512]=U, [k][512:1024]=V
  const int b = blockIdx.x, t = threadIdx.x;
  const int w = t >> 6, l = t & 63;

  {
    int k = t >> 5, c4 = (t & 31) << 2;
    short4 h4 = *(const short4*)(Acat + (size_t)(b * 16 + k) * 640 + c4);
    hT[c4 + 0][k] = bf2f(h4.x); hT[c4 + 1][k] = bf2f(h4.y);
    hT[c4 + 2][k] = bf2f(h4.z); hT[c4 + 3][k] = bf2f(h4.w);
  }
  float4 beA = *(const float4*)(be + (l << 2));
  float4 beB = *(const float4*)(be + 256 + (l << 2));
  float4 waA = *(const float4*)(Wa + (l << 2));
  float4 waB = *(const float4*)(Wa + 256 + (l << 2));
  const float ba0 = ba[0];
  __syncthreads();

  // ---- UV phase: thread t owns output cols {t, t+512}
  {
    float acc[16][2];
#pragma unroll
    for (int k = 0; k < 16; ++k) { acc[k][0] = 0.f; acc[k][1] = 0.f; }
#pragma unroll 2
    for (int d = 0; d < 128; ++d) {
      float wv0 = WUVT[d * 1024 + t];
      float wv1 = WUVT[d * 1024 + t + 512];
      float4 h0 = *(const float4*)&hT[d][0];
      float4 h1 = *(const float4*)&hT[d][4];
      float4 h2 = *(const float4*)&hT[d][8];
      float4 h3 = *(const float4*)&hT[d][12];
      float hv[16] = {h0.x, h0.y, h0.z, h0.w, h1.x, h1.y, h1.z, h1.w,
                      h2.x, h2.y, h2.z, h2.w, h3.x, h3.y, h3.z, h3.w};
#pragma unroll
      for (int k = 0; k < 16; ++k) {
        acc[k][0] = fmaf(hv[k], wv0, acc[k][0]);
        acc[k][1] = fmaf(hv[k], wv1, acc[k][1]);
      }
    }
#pragma unroll
    for (int k = 0; k < 16; ++k) {
      UV[k * 1024 + t] = acc[k][0];
      UV[k * 1024 + t + 512] = acc[k][1];
    }
  }
  __syncthreads();

  // ---- gather phase: wave w -> objects {2w, 2w+1}
#pragma unroll
  for (int kk = 0; kk < 2; ++kk) {
    const int k = (w << 1) + kk;
    float accA[4] = {0.f, 0.f, 0.f, 0.f};
    float accB[4] = {0.f, 0.f, 0.f, 0.f};
#pragma unroll 1
    for (int m = 0; m < 16; ++m) {
      if (m == k) continue;
      int i = k < m ? k : m;
      int j = k < m ? m : k;
      const float* Ui = &UV[i * 1024 + (l << 2)];
      const float* Vj = &UV[j * 1024 + 512 + (l << 2)];
      float4 u0 = *(const float4*)Ui;
      float4 u1 = *(const float4*)(Ui + 256);
      float4 v0 = *(const float4*)Vj;
      float4 v1 = *(const float4*)(Vj + 256);
      float eA[4], eB[4];
      eA[0] = eluf(u0.x + v0.x + beA.x);
      eA[1] = eluf(u0.y + v0.y + beA.y);
      eA[2] = eluf(u0.z + v0.z + beA.z);
      eA[3] = eluf(u0.w + v0.w + beA.w);
      eB[0] = eluf(u1.x + v1.x + beB.x);
      eB[1] = eluf(u1.y + v1.y + beB.y);
      eB[2] = eluf(u1.z + v1.z + beB.z);
      eB[3] = eluf(u1.w + v1.w + beB.w);
      float s;
      s = eA[0] * waA.x;
      s = fmaf(eA[1], waA.y, s);
      s = fmaf(eA[2], waA.z, s);
      s = fmaf(eA[3], waA.w, s);
      s = fmaf(eB[0], waB.x, s);
      s = fmaf(eB[1], waB.y, s);
      s = fmaf(eB[2], waB.z, s);
      s = fmaf(eB[3], waB.w, s);
#pragma unroll
      for (int off = 1; off < 64; off <<= 1) s += __shfl_xor(s, off, 64);
      float att = sigmoidf_(s + ba0);
      accA[0] = fmaf(att, eA[0], accA[0]);
      accA[1] = fmaf(att, eA[1], accA[1]);
      accA[2] = fmaf(att, eA[2], accA[2]);
      accA[3] = fmaf(att, eA[3], accA[3]);
      accB[0] = fmaf(att, eB[0], accB[0]);
      accB[1] = fmaf(att, eB[1], accB[1]);
      accB[2] = fmaf(att, eB[2], accB[2]);
      accB[3] = fmaf(att, eB[3], accB[3]);
    }
    short* dst = Acat + (size_t)(b * 16 + k) * 640 + 128;
    short4 oA, oB;
    oA.x = f2bf(accA[0]); oA.y = f2bf(accA[1]);
    oA.z = f2bf(accA[2]); oA.w = f2bf(accA[3]);
    oB.x = f2bf(accB[0]); oB.y = f2bf(accB[1]);
    oB.z = f2bf(accB[2]); oB.w = f2bf(accB[3]);
    *(short4*)(dst + (l << 2)) = oA;
    *(short4*)(dst + 256 + (l << 2)) = oB;
  }
}

// ---------------------------------------------------------------------------
extern "C" void kernel_launch(void* const* d_in, const int* in_sizes, int n_in,
                              void* d_out, int out_size, void* d_ws, size_t ws_size,
                              hipStream_t stream)
{
  (void)in_sizes; (void)n_in; (void)out_size; (void)ws_size;
  const float* z     = (const float*)d_in[0];
  const float* h0    = (const float*)d_in[1];
  const float* W_obj = (const float*)d_in[2];
  const float* b_obj = (const float*)d_in[3];
  const float* Wih   = (const float*)d_in[4];
  const float* bih   = (const float*)d_in[5];
  const float* Whh   = (const float*)d_in[6];
  const float* bhh   = (const float*)d_in[7];
  const float* We    = (const float*)d_in[8];
  const float* be    = (const float*)d_in[9];
  const float* Wa    = (const float*)d_in[10];
  const float* ba    = (const float*)d_in[11];
  const float* Wc    = (const float*)d_in[12];
  const float* bc    = (const float*)d_in[13];
  const float* Wl    = (const float*)d_in[14];
  const float* bl    = (const float*)d_in[15];
  const float* Wsc   = (const float*)d_in[16];
  const float* bs    = (const float*)d_in[17];
  const float* Wh    = (const float*)d_in[18];
  const float* bh    = (const float*)d_in[19];

  float* ws  = (float*)d_ws;
  float* out = (float*)d_out;

  // ---- workspace layout ----
  float* gi    = ws;                        // 12,582,912 f  [32768][384]
  float* gh    = ws + 12582912;             // 12,582,912 f  [32768][384]
  float* WUVT  = ws + 25165824;             //    131,072 f  [128][1024]
  float* blsh  = ws + 25296896;             //        384 f
  short* bfb   = (short*)(ws + 25297280);   // bf16 region (16B-aligned)
  short* z_bf    = bfb;                     //  4,194,304 sh [32768][128]
  short* h0_bf   = bfb + 4194304;           //  4,194,304 sh
  short* x_bf    = bfb + 8388608;           //  8,388,608 sh [32768][256]
  short* Acat_bf = bfb + 16777216;          // 20,971,520 sh [32768][640]
  short* rel_bf  = bfb + 37748736;          //  4,194,304 sh [32768][128]
  short* Wobj_bf = bfb + 41943040;          //     32,768 sh [256][128]
  short* Wih_bf  = bfb + 41975808;          //     98,304 sh [384][256]
  short* Whh_bf  = bfb + 42074112;          //     49,152 sh [384][128]
  short* Wrel_bf = bfb + 42123264;          //     81,920 sh [128][640]
  short* Wlsh_bf = bfb + 42205184;          //     49,152 sh [384][128]
  // total ~186 MB (< round-2's 219 MB footprint)

  prep_kernel<<<1730, 256, 0, stream>>>(We, Wc, Wl, Wsc, Wh, bl, bs, bh,
                                        W_obj, Wih, Whh,
                                        WUVT, blsh, Wrel_bf, Wlsh_bf,
                                        Wobj_bf, Wih_bf, Whh_bf);
  cvt_zh_kernel<<<8192, 256, 0, stream>>>(z, h0, z_bf, h0_bf);
  // x_bf = elu(z @ W_obj.T + b_obj)          [32768,128]->[.,256] bf16
  mfma_gemm<1, 1><<<dim3(512, 4), 256, 0, stream>>>(z_bf, 128, Wobj_bf, b_obj,
                                                    nullptr, 256, x_bf, nullptr);
  // gi = x @ Wih.T + bih                     [32768,256]->[.,384] f32
  mfma_gemm<0, 0><<<dim3(512, 6), 256, 0, stream>>>(x_bf, 256, Wih_bf, bih,
                                                    gi, 384, nullptr, nullptr);
  // gh = h0 @ Whh.T + bhh                    [32768,128]->[.,384] f32
  mfma_gemm<0, 0><<<dim3(512, 6), 256, 0, stream>>>(h0_bf, 128, Whh_bf, bhh,
                                                    gh, 384, nullptr, nullptr);
  // GRU gates -> h_new (bf16) into Acat_bf[:,0:128]
  gru_gates_kernel<<<4096, 256, 0, stream>>>(gi, gh, h0, Acat_bf);
  // per-batch pair interactions -> E (bf16) into Acat_bf[:,128:640]
  pair_kernel<<<2048, 512, 0, stream>>>(Acat_bf, WUVT, be, Wa, ba);
  // rel_bf = Acat @ Wrel.T + bc              [32768,640]->[.,128] bf16
  mfma_gemm<0, 1><<<dim3(512, 2), 256, 0, stream>>>(Acat_bf, 640, Wrel_bf, bc,
                                                    nullptr, 128, rel_bf, nullptr);
  // [loc|scale|h_out] = rel @ Wlsh.T + blsh -> d_out (f32, split)
  mfma_gemm<0, 2><<<dim3(512, 6), 256, 0, stream>>>(rel_bf, 128, Wlsh_bf, blsh,
                                                    out, 0, nullptr, out + 8388608);
}

// Round 11
// 508.962 us; speedup vs baseline: 3.6241x; 1.0294x over previous
//
#include <hip/hip_runtime.h>

// ---------------------------------------------------------------------------
// RelationalDynamics pipeline for MI355X — bf16-MFMA GEMMs + gather pair.
// B=2048, K=16, Z=128, DIM=256, BK_ALL = 32768 rows.
//
// Round-10 counters: total 524us, absmax 0.015625 (bf16 OK, tolerance has
// headroom). pair_kernel 230us (44%), VALUBusy 81%, MfmaUtil 0 — its UV
// phase (fp32 VALU GEMV, ~2/3 of its work) is MFMA-shaped. Round-11: hoist
// UV = h_new @ WUV2.T into a batched mfma GEMM (f32 out, no bias); pair2
// becomes LDS-load + gather only. UV_all f32 aliases dead gi/gh region.
// ---------------------------------------------------------------------------

typedef __attribute__((ext_vector_type(8))) short bf16x8;
typedef __attribute__((ext_vector_type(4))) float f32x4;

__device__ __forceinline__ float fast_exp(float x) { return __expf(x); }
__device__ __forceinline__ float eluf(float x) {
  return x > 0.0f ? x : fast_exp(x) - 1.0f;
}
__device__ __forceinline__ float sigmoidf_(float x) {
  return __builtin_amdgcn_rcpf(1.0f + fast_exp(-x));
}
__device__ __forceinline__ float tanhf_(float x) {
  return 1.0f - 2.0f * __builtin_amdgcn_rcpf(fast_exp(2.0f * x) + 1.0f);
}
__device__ __forceinline__ short f2bf(float x) {        // RNE f32->bf16
  unsigned u = __builtin_bit_cast(unsigned, x);
  unsigned r = (u + 0x7FFFu + ((u >> 16) & 1u)) >> 16;
  return (short)r;
}
__device__ __forceinline__ float bf2f(short s) {
  return __builtin_bit_cast(float, ((unsigned)(unsigned short)s) << 16);
}

// ------------------------- weight prep -------------------------------------
// WUV2_bf [1024][128]: row o<512 -> We[o][d]+We[o][d+128] (U proj);
//                      row o>=512 -> We[o-512][d+256]+We[o-512][d+384] (V).
// Wrel_bf [128][640]; Wlsh_bf [384][128]; blsh f32 [384]; plus bf16 casts.
__global__ __launch_bounds__(256) void prep_kernel(
    const float* __restrict__ We, const float* __restrict__ Wc,
    const float* __restrict__ Wl, const float* __restrict__ Wsc,
    const float* __restrict__ Wh, const float* __restrict__ bl,
    const float* __restrict__ bs, const float* __restrict__ bh,
    const float* __restrict__ W_obj, const float* __restrict__ Wih,
    const float* __restrict__ Whh,
    float* __restrict__ blsh, short* __restrict__ WUV2_bf,
    short* __restrict__ Wrel_bf, short* __restrict__ Wlsh_bf,
    short* __restrict__ Wobj_bf, short* __restrict__ Wih_bf,
    short* __restrict__ Whh_bf)
{
  int idx = blockIdx.x * 256 + threadIdx.x;
  if (idx < 131072) {                      // WUV2_bf: [1024][128]
    int o = idx >> 7, d = idx & 127;
    float v;
    if (o < 512) v = We[o * 512 + d] + We[o * 512 + d + 128];
    else { int oo = o - 512; v = We[oo * 512 + d + 256] + We[oo * 512 + d + 384]; }
    WUV2_bf[idx] = f2bf(v);
  } else if (idx < 212992) {               // Wrel_bf: 81920
    int j = idx - 131072; int o = j / 640, c = j - o * 640;
    float v = (c < 128) ? (Wc[o * 768 + c] + Wc[o * 768 + c + 128])
                        : Wc[o * 768 + c + 128];
    Wrel_bf[j] = f2bf(v);
  } else if (idx < 262144) {               // Wlsh_bf: 49152
    int j = idx - 212992; int o = j >> 7, c = j & 127;
    float v = (o < 128) ? Wl[o * 128 + c]
            : (o < 256) ? Wsc[(o - 128) * 128 + c]
                        : Wh[(o - 256) * 128 + c];
    Wlsh_bf[j] = f2bf(v);
  } else if (idx < 262528) {               // blsh: 384
    int j = idx - 262144;
    blsh[j] = (j < 128) ? bl[j] : (j < 256) ? bs[j - 128] : bh[j - 256];
  } else if (idx < 295296) {               // Wobj_bf: 32768
    int j = idx - 262528; Wobj_bf[j] = f2bf(W_obj[j]);
  } else if (idx < 393600) {               // Wih_bf: 98304
    int j = idx - 295296; Wih_bf[j] = f2bf(Wih[j]);
  } else if (idx < 442752) {               // Whh_bf: 49152
    int j = idx - 393600; Whh_bf[j] = f2bf(Whh[j]);
  }
}

// ------------------------- z/h0 -> bf16 ------------------------------------
__global__ __launch_bounds__(256) void cvt_zh_kernel(
    const float* __restrict__ z, const float* __restrict__ h0,
    short* __restrict__ z_bf, short* __restrict__ h0_bf)
{
  int g = blockIdx.x * 256 + threadIdx.x;   // 2,097,152 threads x 4 elems
  const float* src; short* dst; int off;
  if (g < 1048576) { src = z;  dst = z_bf;  off = g << 2; }
  else             { src = h0; dst = h0_bf; off = (g - 1048576) << 2; }
  float4 v = *(const float4*)(src + off);
  short4 o;
  o.x = f2bf(v.x); o.y = f2bf(v.y); o.z = f2bf(v.z); o.w = f2bf(v.w);
  *(short4*)(dst + off) = o;
}

// ------------------------- bf16 MFMA GEMM ----------------------------------
// C[M,N] = act(A[M,K](bf16, lda) @ W[N,K](bf16).T + bias). 64x64 tile/4 waves;
// wave w owns rows [bx*64+w*16,+16) x cols [by*64,+64) as 4 col-tiles.
// ACT: 0 none, 1 elu. OUTMODE: 0 f32->C[r*ldc+c]; 1 bf16->Cb[r*ldc+c];
// 2 split: c<256 -> C[r*256+c] (f32), else C2[r*128+c-256] (f32).
// HASBIAS: 0 -> bias ignored (treated as zero).
template<int ACT, int OUTMODE, int HASBIAS>
__global__ __launch_bounds__(256) void mfma_gemm(
    const short* __restrict__ A, int lda, int K,
    const short* __restrict__ W,
    const float* __restrict__ bias,
    float* __restrict__ C, int ldc,
    short* __restrict__ Cb,
    float* __restrict__ C2)
{
  const int t = threadIdx.x;
  const int wv = t >> 6, l = t & 63;
  const int lr = l & 15, lk = l >> 4;
  const int row0 = blockIdx.x * 64 + wv * 16;
  const int col0 = blockIdx.y * 64;

  const short* Ap = A + (size_t)(row0 + lr) * lda + lk * 8;
  const short* Wp = W + (size_t)(col0 + lr) * K + lk * 8;
  const size_t wstep = (size_t)16 * K;

  f32x4 acc0 = {0.f,0.f,0.f,0.f}, acc1 = {0.f,0.f,0.f,0.f};
  f32x4 acc2 = {0.f,0.f,0.f,0.f}, acc3 = {0.f,0.f,0.f,0.f};
  for (int k0 = 0; k0 < K; k0 += 32) {
    bf16x8 a  = *(const bf16x8*)(Ap + k0);
    bf16x8 b0 = *(const bf16x8*)(Wp + k0);
    bf16x8 b1 = *(const bf16x8*)(Wp + wstep + k0);
    bf16x8 b2 = *(const bf16x8*)(Wp + 2 * wstep + k0);
    bf16x8 b3 = *(const bf16x8*)(Wp + 3 * wstep + k0);
    acc0 = __builtin_amdgcn_mfma_f32_16x16x32_bf16(a, b0, acc0, 0, 0, 0);
    acc1 = __builtin_amdgcn_mfma_f32_16x16x32_bf16(a, b1, acc1, 0, 0, 0);
    acc2 = __builtin_amdgcn_mfma_f32_16x16x32_bf16(a, b2, acc2, 0, 0, 0);
    acc3 = __builtin_amdgcn_mfma_f32_16x16x32_bf16(a, b3, acc3, 0, 0, 0);
  }
  f32x4 accs[4] = {acc0, acc1, acc2, acc3};
#pragma unroll
  for (int ct = 0; ct < 4; ++ct) {
    const int c = col0 + ct * 16 + lr;
    const float bv = HASBIAS ? bias[c] : 0.0f;
#pragma unroll
    for (int j = 0; j < 4; ++j) {
      const int r = row0 + lk * 4 + j;
      float x = accs[ct][j] + bv;
      if (ACT == 1) x = eluf(x);
      if (OUTMODE == 0) {
        C[(size_t)r * ldc + c] = x;
      } else if (OUTMODE == 1) {
        Cb[(size_t)r * ldc + c] = f2bf(x);
      } else {
        if (c < 256) C[(size_t)r * 256 + c] = x;
        else         C2[(size_t)r * 128 + (c - 256)] = x;
      }
    }
  }
}

// ------------------------- GRU gates ---------------------------------------
// h_new = (1-u)*n + u*h0 ; writes h_new (bf16) into Acat_bf[:, 0:128] (ld=640)
__global__ __launch_bounds__(256) void gru_gates_kernel(
    const float* __restrict__ gi, const float* __restrict__ gh,
    const float* __restrict__ h0, short* __restrict__ Acat)
{
  int g = blockIdx.x * 256 + threadIdx.x;   // 32768*32 threads
  int r = g >> 5, c = (g & 31) << 2;
  const float* gir = gi + (size_t)r * 384;
  const float* ghr = gh + (size_t)r * 384;
  float4 ir  = *(const float4*)(gir + c);
  float4 iz  = *(const float4*)(gir + 128 + c);
  float4 in_ = *(const float4*)(gir + 256 + c);
  float4 hr  = *(const float4*)(ghr + c);
  float4 hz  = *(const float4*)(ghr + 128 + c);
  float4 hn  = *(const float4*)(ghr + 256 + c);
  float4 h   = *(const float4*)(h0 + (size_t)r * 128 + c);
  float4 o;
  {
    float rg = sigmoidf_(ir.x + hr.x), u = sigmoidf_(iz.x + hz.x);
    float n = tanhf_(in_.x + rg * hn.x);
    o.x = (1.f - u) * n + u * h.x;
  }
  {
    float rg = sigmoidf_(ir.y + hr.y), u = sigmoidf_(iz.y + hz.y);
    float n = tanhf_(in_.y + rg * hn.y);
    o.y = (1.f - u) * n + u * h.y;
  }
  {
    float rg = sigmoidf_(ir.z + hr.z), u = sigmoidf_(iz.z + hz.z);
    float n = tanhf_(in_.z + rg * hn.z);
    o.z = (1.f - u) * n + u * h.z;
  }
  {
    float rg = sigmoidf_(ir.w + hr.w), u = sigmoidf_(iz.w + hz.w);
    float n = tanhf_(in_.w + rg * hn.w);
    o.w = (1.f - u) * n + u * h.w;
  }
  short4 o4;
  o4.x = f2bf(o.x); o4.y = f2bf(o.y); o4.z = f2bf(o.z); o4.w = f2bf(o.w);
  *(short4*)(Acat + (size_t)r * 640 + c) = o4;
}

// ------------------------- gather pair kernel ------------------------------
// One block (512 threads, 8 waves) per batch b. Loads UV[16][1024] (f32,
// from the UV mfma GEMM) into LDS, then wave w gathers E for objects
// {2w, 2w+1}: e = elu(U[i]+V[j]+be), att = sigmoid(<e,Wa>+ba) via shfl_xor,
// accE += att*e. No atomics. Writes E bf16 into Acat[:, 128:640].
__global__ __launch_bounds__(512) void pair2_kernel(
    short* __restrict__ Acat,
    const float* __restrict__ UV_all,  // [32768][1024] f32
    const float* __restrict__ be, const float* __restrict__ Wa,
    const float* __restrict__ ba)
{
  __shared__ float UV[16 * 1024];     // [k][0:512]=U, [k][512:1024]=V; 64KB
  const int b = blockIdx.x, t = threadIdx.x;
  const int w = t >> 6, l = t & 63;

  {
    const float4* src = (const float4*)(UV_all + (size_t)b * 16384);
    float4* dst = (float4*)UV;
#pragma unroll
    for (int i = 0; i < 8; ++i) dst[t + i * 512] = src[t + i * 512];
  }
  float4 beA = *(const float4*)(be + (l << 2));
  float4 beB = *(const float4*)(be + 256 + (l << 2));
  float4 waA = *(const float4*)(Wa + (l << 2));
  float4 waB = *(const float4*)(Wa + 256 + (l << 2));
  const float ba0 = ba[0];
  __syncthreads();

  // ---- gather phase: wave w -> objects {2w, 2w+1}
#pragma unroll
  for (int kk = 0; kk < 2; ++kk) {
    const int k = (w << 1) + kk;
    float accA[4] = {0.f, 0.f, 0.f, 0.f};
    float accB[4] = {0.f, 0.f, 0.f, 0.f};
#pragma unroll 1
    for (int m = 0; m < 16; ++m) {
      if (m == k) continue;
      int i = k < m ? k : m;
      int j = k < m ? m : k;
      const float* Ui = &UV[i * 1024 + (l << 2)];
      const float* Vj = &UV[j * 1024 + 512 + (l << 2)];
      float4 u0 = *(const float4*)Ui;
      float4 u1 = *(const float4*)(Ui + 256);
      float4 v0 = *(const float4*)Vj;
      float4 v1 = *(const float4*)(Vj + 256);
      float eA[4], eB[4];
      eA[0] = eluf(u0.x + v0.x + beA.x);
      eA[1] = eluf(u0.y + v0.y + beA.y);
      eA[2] = eluf(u0.z + v0.z + beA.z);
      eA[3] = eluf(u0.w + v0.w + beA.w);
      eB[0] = eluf(u1.x + v1.x + beB.x);
      eB[1] = eluf(u1.y + v1.y + beB.y);
      eB[2] = eluf(u1.z + v1.z + beB.z);
      eB[3] = eluf(u1.w + v1.w + beB.w);
      float s;
      s = eA[0] * waA.x;
      s = fmaf(eA[1], waA.y, s);
      s = fmaf(eA[2], waA.z, s);
      s = fmaf(eA[3], waA.w, s);
      s = fmaf(eB[0], waB.x, s);
      s = fmaf(eB[1], waB.y, s);
      s = fmaf(eB[2], waB.z, s);
      s = fmaf(eB[3], waB.w, s);
#pragma unroll
      for (int off = 1; off < 64; off <<= 1) s += __shfl_xor(s, off, 64);
      float att = sigmoidf_(s + ba0);
      accA[0] = fmaf(att, eA[0], accA[0]);
      accA[1] = fmaf(att, eA[1], accA[1]);
      accA[2] = fmaf(att, eA[2], accA[2]);
      accA[3] = fmaf(att, eA[3], accA[3]);
      accB[0] = fmaf(att, eB[0], accB[0]);
      accB[1] = fmaf(att, eB[1], accB[1]);
      accB[2] = fmaf(att, eB[2], accB[2]);
      accB[3] = fmaf(att, eB[3], accB[3]);
    }
    short* dst = Acat + (size_t)(b * 16 + k) * 640 + 128;
    short4 oA, oB;
    oA.x = f2bf(accA[0]); oA.y = f2bf(accA[1]);
    oA.z = f2bf(accA[2]); oA.w = f2bf(accA[3]);
    oB.x = f2bf(accB[0]); oB.y = f2bf(accB[1]);
    oB.z = f2bf(accB[2]); oB.w = f2bf(accB[3]);
    *(short4*)(dst + (l << 2)) = oA;
    *(short4*)(dst + 256 + (l << 2)) = oB;
  }
}

// ---------------------------------------------------------------------------
extern "C" void kernel_launch(void* const* d_in, const int* in_sizes, int n_in,
                              void* d_out, int out_size, void* d_ws, size_t ws_size,
                              hipStream_t stream)
{
  (void)in_sizes; (void)n_in; (void)out_size; (void)ws_size;
  const float* z     = (const float*)d_in[0];
  const float* h0    = (const float*)d_in[1];
  const float* W_obj = (const float*)d_in[2];
  const float* b_obj = (const float*)d_in[3];
  const float* Wih   = (const float*)d_in[4];
  const float* bih   = (const float*)d_in[5];
  const float* Whh   = (const float*)d_in[6];
  const float* bhh   = (const float*)d_in[7];
  const float* We    = (const float*)d_in[8];
  const float* be    = (const float*)d_in[9];
  const float* Wa    = (const float*)d_in[10];
  const float* ba    = (const float*)d_in[11];
  const float* Wc    = (const float*)d_in[12];
  const float* bc    = (const float*)d_in[13];
  const float* Wl    = (const float*)d_in[14];
  const float* bl    = (const float*)d_in[15];
  const float* Wsc   = (const float*)d_in[16];
  const float* bs    = (const float*)d_in[17];
  const float* Wh    = (const float*)d_in[18];
  const float* bh    = (const float*)d_in[19];

  float* ws  = (float*)d_ws;
  float* out = (float*)d_out;

  // ---- workspace layout (UV_all f32 aliases dead gi/gh region) ----
  float* gi     = ws;                       // 12,582,912 f  [32768][384]
  float* gh     = ws + 12582912;            // 12,582,912 f  [32768][384]
  float* UV_all = ws;                       // 33,554,432 f  [32768][1024]
  float* blsh   = ws + 33554432;            //        384 f
  short* bfb    = (short*)(ws + 33554816);  // bf16 region (16B-aligned)
  short* z_bf    = bfb;                     //  4,194,304 sh [32768][128]
  short* h0_bf   = bfb + 4194304;           //  4,194,304 sh
  short* x_bf    = bfb + 8388608;           //  8,388,608 sh [32768][256]
  short* Acat_bf = bfb + 16777216;          // 20,971,520 sh [32768][640]
  short* rel_bf  = bfb + 37748736;          //  4,194,304 sh [32768][128]
  short* Wobj_bf = bfb + 41943040;          //     32,768 sh [256][128]
  short* Wih_bf  = bfb + 41975808;          //     98,304 sh [384][256]
  short* Whh_bf  = bfb + 42074112;          //     49,152 sh [384][128]
  short* Wrel_bf = bfb + 42123264;          //     81,920 sh [128][640]
  short* Wlsh_bf = bfb + 42205184;          //     49,152 sh [384][128]
  short* WUV2_bf = bfb + 42254336;          //    131,072 sh [1024][128]
  // total ~209 MB (< proven 219 MB round-0 footprint)

  prep_kernel<<<1730, 256, 0, stream>>>(We, Wc, Wl, Wsc, Wh, bl, bs, bh,
                                        W_obj, Wih, Whh,
                                        blsh, WUV2_bf, Wrel_bf, Wlsh_bf,
                                        Wobj_bf, Wih_bf, Whh_bf);
  cvt_zh_kernel<<<8192, 256, 0, stream>>>(z, h0, z_bf, h0_bf);
  // x_bf = elu(z @ W_obj.T + b_obj)          [32768,128]->[.,256] bf16
  mfma_gemm<1, 1, 1><<<dim3(512, 4), 256, 0, stream>>>(
      z_bf, 128, 128, Wobj_bf, b_obj, nullptr, 256, x_bf, nullptr);
  // gi = x @ Wih.T + bih                     [32768,256]->[.,384] f32
  mfma_gemm<0, 0, 1><<<dim3(512, 6), 256, 0, stream>>>(
      x_bf, 256, 256, Wih_bf, bih, gi, 384, nullptr, nullptr);
  // gh = h0 @ Whh.T + bhh                    [32768,128]->[.,384] f32
  mfma_gemm<0, 0, 1><<<dim3(512, 6), 256, 0, stream>>>(
      h0_bf, 128, 128, Whh_bf, bhh, gh, 384, nullptr, nullptr);
  // GRU gates -> h_new (bf16) into Acat_bf[:,0:128]
  gru_gates_kernel<<<4096, 256, 0, stream>>>(gi, gh, h0, Acat_bf);
  // UV_all = h_new @ WUV2.T (no bias)        [32768,128]->[.,1024] f32
  mfma_gemm<0, 0, 0><<<dim3(512, 16), 256, 0, stream>>>(
      Acat_bf, 640, 128, WUV2_bf, nullptr, UV_all, 1024, nullptr, nullptr);
  // gather: att-weighted E (bf16) into Acat_bf[:,128:640]
  pair2_kernel<<<2048, 512, 0, stream>>>(Acat_bf, UV_all, be, Wa, ba);
  // rel_bf = Acat @ Wrel.T + bc              [32768,640]->[.,128] bf16
  mfma_gemm<0, 1, 1><<<dim3(512, 2), 256, 0, stream>>>(
      Acat_bf, 640, 640, Wrel_bf, bc, nullptr, 128, rel_bf, nullptr);
  // [loc|scale|h_out] = rel @ Wlsh.T + blsh -> d_out (f32, split)
  mfma_gemm<0, 2, 1><<<dim3(512, 6), 256, 0, stream>>>(
      rel_bf, 128, 128, Wlsh_bf, blsh, out, 0, nullptr, out + 8388608);
}

// Round 12
// 411.055 us; speedup vs baseline: 4.4873x; 1.2382x over previous
//
#include <hip/hip_runtime.h>

// ---------------------------------------------------------------------------
// RelationalDynamics pipeline for MI355X — fused bf16-MFMA pipeline.
// B=2048, K=16, Z=128, DIM=256, BK_ALL = 32768 rows.
//
// Round-11 counters: pair2 109us (FETCH 65MB of UV_all re-read, VALU 79%,
// Mfma 0), total 509us with ~400us in GEMM+materialization traffic
// (gi/gh 100MB f32 round-trip, UV_all 134MB write + 65MB fetch).
// Round-12: (1) fuse UV GEMM into pair2 (32 MFMA/wave, registers->LDS,
// kills UV_all entirely; MFMA pipe was idle there — m114 co-schedule);
// (2) fuse gi+gh+gates into gru_fused (lane owns col-tiles {ct,ct+8,ct+16}
// = the (c,c+128,c+256) gate triple; gates in-register, h_new bf16 out).
// Deletes ~330MB HBM traffic + 3 dispatches. Same arithmetic => same absmax.
// ---------------------------------------------------------------------------

typedef __attribute__((ext_vector_type(8))) short bf16x8;
typedef __attribute__((ext_vector_type(4))) float f32x4;

__device__ __forceinline__ float fast_exp(float x) { return __expf(x); }
__device__ __forceinline__ float eluf(float x) {
  return x > 0.0f ? x : fast_exp(x) - 1.0f;
}
__device__ __forceinline__ float sigmoidf_(float x) {
  return __builtin_amdgcn_rcpf(1.0f + fast_exp(-x));
}
__device__ __forceinline__ float tanhf_(float x) {
  return 1.0f - 2.0f * __builtin_amdgcn_rcpf(fast_exp(2.0f * x) + 1.0f);
}
__device__ __forceinline__ short f2bf(float x) {        // RNE f32->bf16
  unsigned u = __builtin_bit_cast(unsigned, x);
  unsigned r = (u + 0x7FFFu + ((u >> 16) & 1u)) >> 16;
  return (short)r;
}

// ------------------------- weight prep -------------------------------------
// WUV2_bf [1024][128]: row o<512 -> We[o][d]+We[o][d+128] (U proj);
//                      row o>=512 -> We[o-512][d+256]+We[o-512][d+384] (V).
// Wrel_bf [128][640]; Wlsh_bf [384][128]; blsh f32 [384]; plus bf16 casts.
__global__ __launch_bounds__(256) void prep_kernel(
    const float* __restrict__ We, const float* __restrict__ Wc,
    const float* __restrict__ Wl, const float* __restrict__ Wsc,
    const float* __restrict__ Wh, const float* __restrict__ bl,
    const float* __restrict__ bs, const float* __restrict__ bh,
    const float* __restrict__ W_obj, const float* __restrict__ Wih,
    const float* __restrict__ Whh,
    float* __restrict__ blsh, short* __restrict__ WUV2_bf,
    short* __restrict__ Wrel_bf, short* __restrict__ Wlsh_bf,
    short* __restrict__ Wobj_bf, short* __restrict__ Wih_bf,
    short* __restrict__ Whh_bf)
{
  int idx = blockIdx.x * 256 + threadIdx.x;
  if (idx < 131072) {                      // WUV2_bf: [1024][128]
    int o = idx >> 7, d = idx & 127;
    float v;
    if (o < 512) v = We[o * 512 + d] + We[o * 512 + d + 128];
    else { int oo = o - 512; v = We[oo * 512 + d + 256] + We[oo * 512 + d + 384]; }
    WUV2_bf[idx] = f2bf(v);
  } else if (idx < 212992) {               // Wrel_bf: 81920
    int j = idx - 131072; int o = j / 640, c = j - o * 640;
    float v = (c < 128) ? (Wc[o * 768 + c] + Wc[o * 768 + c + 128])
                        : Wc[o * 768 + c + 128];
    Wrel_bf[j] = f2bf(v);
  } else if (idx < 262144) {               // Wlsh_bf: 49152
    int j = idx - 212992; int o = j >> 7, c = j & 127;
    float v = (o < 128) ? Wl[o * 128 + c]
            : (o < 256) ? Wsc[(o - 128) * 128 + c]
                        : Wh[(o - 256) * 128 + c];
    Wlsh_bf[j] = f2bf(v);
  } else if (idx < 262528) {               // blsh: 384
    int j = idx - 262144;
    blsh[j] = (j < 128) ? bl[j] : (j < 256) ? bs[j - 128] : bh[j - 256];
  } else if (idx < 295296) {               // Wobj_bf: 32768
    int j = idx - 262528; Wobj_bf[j] = f2bf(W_obj[j]);
  } else if (idx < 393600) {               // Wih_bf: 98304
    int j = idx - 295296; Wih_bf[j] = f2bf(Wih[j]);
  } else if (idx < 442752) {               // Whh_bf: 49152
    int j = idx - 393600; Whh_bf[j] = f2bf(Whh[j]);
  }
}

// ------------------------- z/h0 -> bf16 ------------------------------------
__global__ __launch_bounds__(256) void cvt_zh_kernel(
    const float* __restrict__ z, const float* __restrict__ h0,
    short* __restrict__ z_bf, short* __restrict__ h0_bf)
{
  int g = blockIdx.x * 256 + threadIdx.x;   // 2,097,152 threads x 4 elems
  const float* src; short* dst; int off;
  if (g < 1048576) { src = z;  dst = z_bf;  off = g << 2; }
  else             { src = h0; dst = h0_bf; off = (g - 1048576) << 2; }
  float4 v = *(const float4*)(src + off);
  short4 o;
  o.x = f2bf(v.x); o.y = f2bf(v.y); o.z = f2bf(v.z); o.w = f2bf(v.w);
  *(short4*)(dst + off) = o;
}

// ------------------------- bf16 MFMA GEMM ----------------------------------
// C[M,N] = act(A[M,K](bf16, lda) @ W[N,K](bf16).T + bias). 64x64 tile/4 waves.
// ACT: 0 none, 1 elu. OUTMODE: 0 f32->C[r*ldc+c]; 1 bf16->Cb[r*ldc+c];
// 2 split: c<256 -> C[r*256+c] (f32), else C2[r*128+c-256] (f32).
template<int ACT, int OUTMODE>
__global__ __launch_bounds__(256) void mfma_gemm(
    const short* __restrict__ A, int lda, int K,
    const short* __restrict__ W,
    const float* __restrict__ bias,
    float* __restrict__ C, int ldc,
    short* __restrict__ Cb,
    float* __restrict__ C2)
{
  const int t = threadIdx.x;
  const int wv = t >> 6, l = t & 63;
  const int lr = l & 15, lk = l >> 4;
  const int row0 = blockIdx.x * 64 + wv * 16;
  const int col0 = blockIdx.y * 64;

  const short* Ap = A + (size_t)(row0 + lr) * lda + lk * 8;
  const short* Wp = W + (size_t)(col0 + lr) * K + lk * 8;
  const size_t wstep = (size_t)16 * K;

  f32x4 acc0 = {0.f,0.f,0.f,0.f}, acc1 = {0.f,0.f,0.f,0.f};
  f32x4 acc2 = {0.f,0.f,0.f,0.f}, acc3 = {0.f,0.f,0.f,0.f};
  for (int k0 = 0; k0 < K; k0 += 32) {
    bf16x8 a  = *(const bf16x8*)(Ap + k0);
    bf16x8 b0 = *(const bf16x8*)(Wp + k0);
    bf16x8 b1 = *(const bf16x8*)(Wp + wstep + k0);
    bf16x8 b2 = *(const bf16x8*)(Wp + 2 * wstep + k0);
    bf16x8 b3 = *(const bf16x8*)(Wp + 3 * wstep + k0);
    acc0 = __builtin_amdgcn_mfma_f32_16x16x32_bf16(a, b0, acc0, 0, 0, 0);
    acc1 = __builtin_amdgcn_mfma_f32_16x16x32_bf16(a, b1, acc1, 0, 0, 0);
    acc2 = __builtin_amdgcn_mfma_f32_16x16x32_bf16(a, b2, acc2, 0, 0, 0);
    acc3 = __builtin_amdgcn_mfma_f32_16x16x32_bf16(a, b3, acc3, 0, 0, 0);
  }
  f32x4 accs[4] = {acc0, acc1, acc2, acc3};
#pragma unroll
  for (int ct = 0; ct < 4; ++ct) {
    const int c = col0 + ct * 16 + lr;
    const float bv = bias[c];
#pragma unroll
    for (int j = 0; j < 4; ++j) {
      const int r = row0 + lk * 4 + j;
      float x = accs[ct][j] + bv;
      if (ACT == 1) x = eluf(x);
      if (OUTMODE == 0) {
        C[(size_t)r * ldc + c] = x;
      } else if (OUTMODE == 1) {
        Cb[(size_t)r * ldc + c] = f2bf(x);
      } else {
        if (c < 256) C[(size_t)r * 256 + c] = x;
        else         C2[(size_t)r * 128 + (c - 256)] = x;
      }
    }
  }
}

// ------------------------- fused GRU (gi + gh + gates) ---------------------
// One block = 64 rows x all 384 cols of BOTH GEMMs. Wave wv owns rows
// [bx*64+wv*16,+16). Loop ct=0..7: compute col-tiles {ct, ct+8, ct+16} of
// gi (K=256) and gh (K=128); a lane then holds the (c, c+128, c+256) gate
// triple in-register -> gates -> h_new bf16 into Acat[:,0:128] (ld 640).
__global__ __launch_bounds__(256) void gru_fused(
    const short* __restrict__ x_bf,   // [32768][256]
    const short* __restrict__ h0_bf,  // [32768][128]
    const float* __restrict__ h0,     // [32768][128] f32
    const short* __restrict__ Wih_bf, // [384][256]
    const short* __restrict__ Whh_bf, // [384][128]
    const float* __restrict__ bih, const float* __restrict__ bhh,
    short* __restrict__ Acat)
{
  const int t = threadIdx.x;
  const int wv = t >> 6, l = t & 63;
  const int lr = l & 15, lk = l >> 4;
  const int row0 = blockIdx.x * 64 + wv * 16;

  const short* Ax = x_bf + (size_t)(row0 + lr) * 256 + lk * 8;
  const short* Ah = h0_bf + (size_t)(row0 + lr) * 128 + lk * 8;
  bf16x8 ax[8], ah[4];
#pragma unroll
  for (int s = 0; s < 8; ++s) ax[s] = *(const bf16x8*)(Ax + s * 32);
#pragma unroll
  for (int s = 0; s < 4; ++s) ah[s] = *(const bf16x8*)(Ah + s * 32);

#pragma unroll 1
  for (int ct = 0; ct < 8; ++ct) {
    const int c = ct * 16 + lr;     // c in [0,128)
    f32x4 gir = {0.f,0.f,0.f,0.f}, giz = {0.f,0.f,0.f,0.f}, gin = {0.f,0.f,0.f,0.f};
    f32x4 ghr = {0.f,0.f,0.f,0.f}, ghz = {0.f,0.f,0.f,0.f}, ghn = {0.f,0.f,0.f,0.f};
    const short* Wi0 = Wih_bf + (size_t)(c) * 256 + lk * 8 - lr * 256 + lr * 256; // = (ct*16+lr)*256+lk*8
    const short* Wir = Wih_bf + (size_t)(ct * 16 + lr) * 256 + lk * 8;
    const short* Wiz = Wih_bf + (size_t)(128 + ct * 16 + lr) * 256 + lk * 8;
    const short* Win = Wih_bf + (size_t)(256 + ct * 16 + lr) * 256 + lk * 8;
    (void)Wi0;
#pragma unroll
    for (int s = 0; s < 8; ++s) {
      gir = __builtin_amdgcn_mfma_f32_16x16x32_bf16(ax[s], *(const bf16x8*)(Wir + s * 32), gir, 0, 0, 0);
      giz = __builtin_amdgcn_mfma_f32_16x16x32_bf16(ax[s], *(const bf16x8*)(Wiz + s * 32), giz, 0, 0, 0);
      gin = __builtin_amdgcn_mfma_f32_16x16x32_bf16(ax[s], *(const bf16x8*)(Win + s * 32), gin, 0, 0, 0);
    }
    const short* Whr = Whh_bf + (size_t)(ct * 16 + lr) * 128 + lk * 8;
    const short* Whz = Whh_bf + (size_t)(128 + ct * 16 + lr) * 128 + lk * 8;
    const short* Whn = Whh_bf + (size_t)(256 + ct * 16 + lr) * 128 + lk * 8;
#pragma unroll
    for (int s = 0; s < 4; ++s) {
      ghr = __builtin_amdgcn_mfma_f32_16x16x32_bf16(ah[s], *(const bf16x8*)(Whr + s * 32), ghr, 0, 0, 0);
      ghz = __builtin_amdgcn_mfma_f32_16x16x32_bf16(ah[s], *(const bf16x8*)(Whz + s * 32), ghz, 0, 0, 0);
      ghn = __builtin_amdgcn_mfma_f32_16x16x32_bf16(ah[s], *(const bf16x8*)(Whn + s * 32), ghn, 0, 0, 0);
    }
    const float br = bih[c], bz = bih[c + 128], bn = bih[c + 256];
    const float cr = bhh[c], cz = bhh[c + 128], cn = bhh[c + 256];
#pragma unroll
    for (int j = 0; j < 4; ++j) {
      const int r = row0 + lk * 4 + j;
      float rg = sigmoidf_((gir[j] + br) + (ghr[j] + cr));
      float u  = sigmoidf_((giz[j] + bz) + (ghz[j] + cz));
      float n  = tanhf_((gin[j] + bn) + rg * (ghn[j] + cn));
      float hv = h0[(size_t)r * 128 + c];
      Acat[(size_t)r * 640 + c] = f2bf((1.f - u) * n + u * hv);
    }
  }
}

// ------------------------- pair kernel (fused UV + gather) -----------------
// One block (512 threads, 8 waves) per batch b.
// Phase 1 (MFMA): UV[16][1024] = h[16][128] @ WUV2[1024][128].T.
//   Wave w owns cols [w*128, +128) as 8 col-tiles; M=16 = one fragment;
//   32 MFMAs/wave, results written to LDS.
// Phase 2 (gather): wave w -> objects {2w, 2w+1}: e = elu(U[i]+V[j]+be),
//   att = sigmoid(<e,Wa>+ba) via shfl_xor, accE += att*e. E bf16 -> Acat.
__global__ __launch_bounds__(512) void pair2_kernel(
    short* __restrict__ Acat,
    const short* __restrict__ WUV2_bf, // [1024][128] bf16
    const float* __restrict__ be, const float* __restrict__ Wa,
    const float* __restrict__ ba)
{
  __shared__ float UV[16 * 1024];     // [k][0:512]=U, [k][512:1024]=V; 64KB
  const int b = blockIdx.x, t = threadIdx.x;
  const int w = t >> 6, l = t & 63;
  const int lr = l & 15, lk = l >> 4;

  // ---- phase 1: UV via MFMA (A rows = 16 objects of this batch)
  {
    const short* Ap = Acat + (size_t)(b * 16 + lr) * 640 + lk * 8;
    bf16x8 ah[4];
#pragma unroll
    for (int s = 0; s < 4; ++s) ah[s] = *(const bf16x8*)(Ap + s * 32);
#pragma unroll
    for (int ct = 0; ct < 8; ++ct) {
      const int col0 = w * 128 + ct * 16;
      const short* Wp = WUV2_bf + (size_t)(col0 + lr) * 128 + lk * 8;
      f32x4 acc = {0.f, 0.f, 0.f, 0.f};
#pragma unroll
      for (int s = 0; s < 4; ++s)
        acc = __builtin_amdgcn_mfma_f32_16x16x32_bf16(ah[s], *(const bf16x8*)(Wp + s * 32), acc, 0, 0, 0);
#pragma unroll
      for (int j = 0; j < 4; ++j)
        UV[(lk * 4 + j) * 1024 + col0 + lr] = acc[j];
    }
  }
  float4 beA = *(const float4*)(be + (l << 2));
  float4 beB = *(const float4*)(be + 256 + (l << 2));
  float4 waA = *(const float4*)(Wa + (l << 2));
  float4 waB = *(const float4*)(Wa + 256 + (l << 2));
  const float ba0 = ba[0];
  __syncthreads();

  // ---- phase 2: gather, wave w -> objects {2w, 2w+1}
#pragma unroll
  for (int kk = 0; kk < 2; ++kk) {
    const int k = (w << 1) + kk;
    float accA[4] = {0.f, 0.f, 0.f, 0.f};
    float accB[4] = {0.f, 0.f, 0.f, 0.f};
#pragma unroll 1
    for (int m = 0; m < 16; ++m) {
      if (m == k) continue;
      int i = k < m ? k : m;
      int j = k < m ? m : k;
      const float* Ui = &UV[i * 1024 + (l << 2)];
      const float* Vj = &UV[j * 1024 + 512 + (l << 2)];
      float4 u0 = *(const float4*)Ui;
      float4 u1 = *(const float4*)(Ui + 256);
      float4 v0 = *(const float4*)Vj;
      float4 v1 = *(const float4*)(Vj + 256);
      float eA[4], eB[4];
      eA[0] = eluf(u0.x + v0.x + beA.x);
      eA[1] = eluf(u0.y + v0.y + beA.y);
      eA[2] = eluf(u0.z + v0.z + beA.z);
      eA[3] = eluf(u0.w + v0.w + beA.w);
      eB[0] = eluf(u1.x + v1.x + beB.x);
      eB[1] = eluf(u1.y + v1.y + beB.y);
      eB[2] = eluf(u1.z + v1.z + beB.z);
      eB[3] = eluf(u1.w + v1.w + beB.w);
      float s;
      s = eA[0] * waA.x;
      s = fmaf(eA[1], waA.y, s);
      s = fmaf(eA[2], waA.z, s);
      s = fmaf(eA[3], waA.w, s);
      s = fmaf(eB[0], waB.x, s);
      s = fmaf(eB[1], waB.y, s);
      s = fmaf(eB[2], waB.z, s);
      s = fmaf(eB[3], waB.w, s);
#pragma unroll
      for (int off = 1; off < 64; off <<= 1) s += __shfl_xor(s, off, 64);
      float att = sigmoidf_(s + ba0);
      accA[0] = fmaf(att, eA[0], accA[0]);
      accA[1] = fmaf(att, eA[1], accA[1]);
      accA[2] = fmaf(att, eA[2], accA[2]);
      accA[3] = fmaf(att, eA[3], accA[3]);
      accB[0] = fmaf(att, eB[0], accB[0]);
      accB[1] = fmaf(att, eB[1], accB[1]);
      accB[2] = fmaf(att, eB[2], accB[2]);
      accB[3] = fmaf(att, eB[3], accB[3]);
    }
    short* dst = Acat + (size_t)(b * 16 + k) * 640 + 128;
    short4 oA, oB;
    oA.x = f2bf(accA[0]); oA.y = f2bf(accA[1]);
    oA.z = f2bf(accA[2]); oA.w = f2bf(accA[3]);
    oB.x = f2bf(accB[0]); oB.y = f2bf(accB[1]);
    oB.z = f2bf(accB[2]); oB.w = f2bf(accB[3]);
    *(short4*)(dst + (l << 2)) = oA;
    *(short4*)(dst + 256 + (l << 2)) = oB;
  }
}

// ---------------------------------------------------------------------------
extern "C" void kernel_launch(void* const* d_in, const int* in_sizes, int n_in,
                              void* d_out, int out_size, void* d_ws, size_t ws_size,
                              hipStream_t stream)
{
  (void)in_sizes; (void)n_in; (void)out_size; (void)ws_size;
  const float* z     = (const float*)d_in[0];
  const float* h0    = (const float*)d_in[1];
  const float* W_obj = (const float*)d_in[2];
  const float* b_obj = (const float*)d_in[3];
  const float* Wih   = (const float*)d_in[4];
  const float* bih   = (const float*)d_in[5];
  const float* Whh   = (const float*)d_in[6];
  const float* bhh   = (const float*)d_in[7];
  const float* We    = (const float*)d_in[8];
  const float* be    = (const float*)d_in[9];
  const float* Wa    = (const float*)d_in[10];
  const float* ba    = (const float*)d_in[11];
  const float* Wc    = (const float*)d_in[12];
  const float* bc    = (const float*)d_in[13];
  const float* Wl    = (const float*)d_in[14];
  const float* bl    = (const float*)d_in[15];
  const float* Wsc   = (const float*)d_in[16];
  const float* bs    = (const float*)d_in[17];
  const float* Wh    = (const float*)d_in[18];
  const float* bh    = (const float*)d_in[19];

  float* ws  = (float*)d_ws;
  float* out = (float*)d_out;

  // ---- workspace layout ----
  float* blsh = ws;                         //        384 f
  short* bfb  = (short*)(ws + 384);         // bf16 region (16B-aligned)
  short* z_bf    = bfb;                     //  4,194,304 sh [32768][128]
  short* h0_bf   = bfb + 4194304;           //  4,194,304 sh
  short* x_bf    = bfb + 8388608;           //  8,388,608 sh [32768][256]
  short* Acat_bf = bfb + 16777216;          // 20,971,520 sh [32768][640]
  short* rel_bf  = bfb + 37748736;          //  4,194,304 sh [32768][128]
  short* Wobj_bf = bfb + 41943040;          //     32,768 sh [256][128]
  short* Wih_bf  = bfb + 41975808;          //     98,304 sh [384][256]
  short* Whh_bf  = bfb + 42074112;          //     49,152 sh [384][128]
  short* Wrel_bf = bfb + 42123264;          //     81,920 sh [128][640]
  short* Wlsh_bf = bfb + 42205184;          //     49,152 sh [384][128]
  short* WUV2_bf = bfb + 42254336;          //    131,072 sh [1024][128]
  // total ~85 MB

  prep_kernel<<<1730, 256, 0, stream>>>(We, Wc, Wl, Wsc, Wh, bl, bs, bh,
                                        W_obj, Wih, Whh,
                                        blsh, WUV2_bf, Wrel_bf, Wlsh_bf,
                                        Wobj_bf, Wih_bf, Whh_bf);
  cvt_zh_kernel<<<8192, 256, 0, stream>>>(z, h0, z_bf, h0_bf);
  // x_bf = elu(z @ W_obj.T + b_obj)          [32768,128]->[.,256] bf16
  mfma_gemm<1, 1><<<dim3(512, 4), 256, 0, stream>>>(
      z_bf, 128, 128, Wobj_bf, b_obj, nullptr, 256, x_bf, nullptr);
  // fused GRU: gi+gh GEMMs + gates -> h_new (bf16) into Acat_bf[:,0:128]
  gru_fused<<<512, 256, 0, stream>>>(x_bf, h0_bf, h0, Wih_bf, Whh_bf,
                                     bih, bhh, Acat_bf);
  // fused UV(MFMA)+gather: E (bf16) into Acat_bf[:,128:640]
  pair2_kernel<<<2048, 512, 0, stream>>>(Acat_bf, WUV2_bf, be, Wa, ba);
  // rel_bf = Acat @ Wrel.T + bc              [32768,640]->[.,128] bf16
  mfma_gemm<0, 1><<<dim3(512, 2), 256, 0, stream>>>(
      Acat_bf, 640, 640, Wrel_bf, bc, nullptr, 128, rel_bf, nullptr);
  // [loc|scale|h_out] = rel @ Wlsh.T + blsh -> d_out (f32, split)
  mfma_gemm<0, 2><<<dim3(512, 6), 256, 0, stream>>>(
      rel_bf, 128, 128, Wlsh_bf, blsh, out, 0, nullptr, out + 8388608);
}